// Round 15
// baseline (632.894 us; speedup 1.0000x reference)
//
#include <hip/hip_runtime.h>
#include <math.h>

typedef short  s16x4 __attribute__((ext_vector_type(4)));
typedef short  s16x8 __attribute__((ext_vector_type(8)));
typedef float  f32x4 __attribute__((ext_vector_type(4)));

// ---------------- workspace float offsets ----------------
static const size_t PE25_  = 0;
static const size_t SPAPE_ = 2048;
static const size_t X_     = 38912;
static const size_t CAV_   = 53312;
static const size_t PETOK_ = 54272;
static const size_t W9C_   = 349184;
static const size_t W9S_   = 459776;
static const size_t BUF_   = 754688;
static const size_t BLK_   = 1676288;
static const size_t ATOK_  = 2597888;
static const size_t TNF_   = 3519488;
static const size_t STOK_  = 4441088;
static const size_t STOK2_ = 6284288;
static const size_t QKV_   = 9970688;    // bf16 [14400][384]
static const size_t WS_FLOATS = 15500288;
static const size_t T0_ = QKV_ + 2764800;
static const size_t T1_ = T0_ + 921600;
static const size_t ZP_ = QKV_;
static const size_t H0_ = STOK_;
static const size_t H1_ = STOK2_;

// ---------------- bf16 split helpers ----------------
__device__ inline ushort f2bf(float x) {
  unsigned u = __float_as_uint(x);
  u += 0x7fffu + ((u >> 16) & 1u);
  return (ushort)(u >> 16);
}
__device__ inline float bf2f(ushort h) { return __uint_as_float(((unsigned)h) << 16); }

__device__ inline void store_split(char* p, f32x4 v) {
  s16x4 hi, lo;
  #pragma unroll
  for (int e = 0; e < 4; ++e) {
    float x = v[e];
    ushort h = f2bf(x);
    ushort l = f2bf(x - bf2f(h));
    hi[e] = (short)h; lo[e] = (short)l;
  }
  *(s16x4*)p = hi;
  *(s16x4*)(p + 1024) = lo;
}

__device__ inline void scatter_split(char* base, int rr, int c6, float v) {
  ushort hi = f2bf(v);
  ushort lo = f2bf(v - bf2f(hi));
  int ks = c6 >> 5, kh = (c6 >> 4) & 1, k4 = (c6 >> 2) & 3;
  int lane2 = (k4 >> 1)*32 + ((rr & 15) << 1) + (k4 & 1);
  int byt = (((rr >> 4)*2 + ks) << 11) + (kh << 9) + (lane2 << 3) + (c6 & 3)*2;
  *(ushort*)(base + byt) = hi;
  *(ushort*)(base + byt + 1024) = lo;
}

__device__ inline void ld_bf16x16(const ushort* p, float* dst) {
  s16x8 a = *(const s16x8*)p;
  s16x8 b = *(const s16x8*)(p + 8);
  #pragma unroll
  for (int e = 0; e < 8; ++e) { dst[e] = bf2f((ushort)a[e]); dst[8 + e] = bf2f((ushort)b[e]); }
}

__device__ inline void slot_decode(int i, int wave, int lane,
                                   int& row, int& kof, int& wo) {
  int idx = (i << 2) + wave;
  int msub = idx >> 2, ks = (idx >> 1) & 1, kh = idx & 1;
  int rsub = (lane >> 1) & 15;
  int ksub = ((lane >> 5) << 3) + ((lane & 1) << 2);
  row = (msub << 4) + rsub;
  kof = (ks << 5) + (kh << 4) + ksub;
  wo = ((msub * 2 + ks) << 11) + (kh << 9) + (lane << 3);
}

__device__ inline void mfma_step(const char* ldsA, const char* ldsB, int lane,
                                 int wr, int wc, f32x4 acc[2][2]) {
  #pragma unroll
  for (int ks = 0; ks < 2; ++ks) {
    s16x8 ah[2], al[2], bh[2], bl[2];
    #pragma unroll
    for (int i = 0; i < 2; ++i) {
      const char* pa = ldsA + (((wr*2 + i)*2 + ks) << 11) + (lane << 4);
      ah[i] = *(const s16x8*)pa;
      al[i] = *(const s16x8*)(pa + 1024);
      const char* pb = ldsB + (((wc*2 + i)*2 + ks) << 11) + (lane << 4);
      bh[i] = *(const s16x8*)pb;
      bl[i] = *(const s16x8*)(pb + 1024);
    }
    #pragma unroll
    for (int i = 0; i < 2; ++i) {
      #pragma unroll
      for (int j = 0; j < 2; ++j) {
        acc[i][j] = __builtin_amdgcn_mfma_f32_16x16x32_bf16(ah[i], bh[j], acc[i][j], 0, 0, 0);
        acc[i][j] = __builtin_amdgcn_mfma_f32_16x16x32_bf16(ah[i], bl[j], acc[i][j], 0, 0, 0);
        acc[i][j] = __builtin_amdgcn_mfma_f32_16x16x32_bf16(al[i], bh[j], acc[i][j], 0, 0, 0);
      }
    }
  }
}

// epilogue; act: 0 none, 1 relu, 2 lrelu, 3 final-scatter, 4 bf16-store
__device__ inline void epilogue(f32x4 acc[2][2], const float* bias, const float* res,
                                float* out, int N, int m0, int n0,
                                int wr, int wc, int lane, int act) {
  int colb = n0 + wc*32 + (lane & 15);
  int rowb = m0 + wr*32 + ((lane >> 4) << 2);
  #pragma unroll
  for (int j = 0; j < 2; ++j) {
    int cc = colb + j*16;
    if (cc >= N) continue;
    float bv = bias ? bias[cc] : 0.f;
    #pragma unroll
    for (int i = 0; i < 2; ++i) {
      #pragma unroll
      for (int r = 0; r < 4; ++r) {
        int rr = rowb + i*16 + r;
        float v = acc[i][j][r] + bv;
        if (act == 1) v = fmaxf(v, 0.f);
        else if (act == 2) v = v > 0.f ? v : 0.2f*v;
        if (res) v += res[(long)rr*N + cc];
        if (act == 3) {
          int hh = rr / 48, ww2 = rr % 48, q = cc / 3, ch = cc % 3;
          out[ch*57600 + ((q/5)*48 + hh)*240 + (q%5)*48 + ww2] = v;
        } else if (act == 4) {
          ((ushort*)out)[(long)rr*N + cc] = f2bf(v);
        } else {
          out[(long)rr*N + cc] = v;
        }
      }
    }
  }
}

// ---------------- qkvg: qkv GEMM grouped by A-plane type ----------------
template<int K>
__global__ __launch_bounds__(256) void qkvg_k(
    const float* __restrict__ A, const float* __restrict__ pe, int pe_mode,
    const float* __restrict__ g, const float* __restrict__ bb,
    const float* __restrict__ W, float* __restrict__ out,
    int NTr0, int NTr1, int N, int Mreal, int Mpad) {
  constexpr int NCH = K / 64;
  __shared__ char Apl[NCH * 16384];
  __shared__ char Bp[16384];
  __shared__ float sw_[4][64][2];
  __shared__ float sf_[64][2];
  int bid = blockIdx.x;
  int type = bid / Mpad, m = bid % Mpad;
  if (m >= Mreal) return;
  int m0 = m*64;
  int NTr = type ? NTr1 : NTr0;
  int ntbase = type ? NTr0 : 0;
  int t = threadIdx.x, lane = t & 63, wave = t >> 6;
  int wr = wave >> 1, wc = wave & 1;

  if (type == 0) {
    f32x4 rv[NCH][4];
    float sA[4], sQ[4];
    #pragma unroll
    for (int i = 0; i < 4; ++i) { sA[i] = 0.f; sQ[i] = 0.f; }
    #pragma unroll
    for (int ch = 0; ch < NCH; ++ch)
      #pragma unroll
      for (int i = 0; i < 4; ++i) {
        int row, kof, wo;
        slot_decode(i, wave, lane, row, kof, wo);
        int gk = ch*64 + kof;
        f32x4 av = *(const f32x4*)&A[(long)(m0 + row)*K + gk];
        if (pe_mode == 0)      av += *(const f32x4*)&pe[(long)(m0/576)*K + gk];
        else                   av += *(const f32x4*)&pe[(long)(m0%576 + row)*K + gk];
        rv[ch][i] = av;
        #pragma unroll
        for (int e = 0; e < 4; ++e) { sA[i] += av[e]; sQ[i] = fmaf(av[e], av[e], sQ[i]); }
      }
    #pragma unroll
    for (int i = 0; i < 4; ++i) {
      float s = sA[i], q = sQ[i];
      s += __shfl_xor(s, 1, 64);  q += __shfl_xor(q, 1, 64);
      s += __shfl_xor(s, 32, 64); q += __shfl_xor(q, 32, 64);
      if ((lane & 1) == 0 && lane < 32) {
        int row = i*16 + (lane >> 1);
        sw_[wave][row][0] = s; sw_[wave][row][1] = q;
      }
    }
    __syncthreads();
    if (t < 64) {
      float s = sw_[0][t][0] + sw_[1][t][0] + sw_[2][t][0] + sw_[3][t][0];
      float q = sw_[0][t][1] + sw_[1][t][1] + sw_[2][t][1] + sw_[3][t][1];
      float mean = s / K, var = q / K - mean*mean;
      sf_[t][0] = mean; sf_[t][1] = rsqrtf(var + 1e-5f);
    }
    __syncthreads();
    #pragma unroll
    for (int ch = 0; ch < NCH; ++ch)
      #pragma unroll
      for (int i = 0; i < 4; ++i) {
        int row, kof, wo;
        slot_decode(i, wave, lane, row, kof, wo);
        int gk = ch*64 + kof;
        float mean = sf_[row][0], rstd = sf_[row][1];
        f32x4 gv = *(const f32x4*)&g[gk];
        f32x4 bv = *(const f32x4*)&bb[gk];
        f32x4 nv;
        #pragma unroll
        for (int e = 0; e < 4; ++e) nv[e] = (rv[ch][i][e] - mean)*rstd*gv[e] + bv[e];
        store_split(Apl + ch*16384 + wo, nv);
      }
  } else {
    #pragma unroll
    for (int ch = 0; ch < NCH; ++ch)
      #pragma unroll
      for (int i = 0; i < 4; ++i) {
        int row, kof, wo;
        slot_decode(i, wave, lane, row, kof, wo);
        f32x4 av = *(const f32x4*)&A[(long)(m0 + row)*K + ch*64 + kof];
        store_split(Apl + ch*16384 + wo, av);
      }
  }

  int S = NTr * NCH;
  f32x4 pb[4];
  #pragma unroll
  for (int i = 0; i < 4; ++i) {
    int row, kof, wo;
    slot_decode(i, wave, lane, row, kof, wo);
    pb[i] = *(const f32x4*)&W[(long)(ntbase*64 + row)*K + kof];
  }
  f32x4 acc[2][2];
  #pragma unroll
  for (int i = 0; i < 2; ++i)
    #pragma unroll
    for (int j = 0; j < 2; ++j) acc[i][j] = (f32x4){0.f,0.f,0.f,0.f};
  for (int s = 0; s < S; ++s) {
    int nt = s / NCH, ch = s % NCH;
    __syncthreads();
    #pragma unroll
    for (int i = 0; i < 4; ++i) {
      int row, kof, wo;
      slot_decode(i, wave, lane, row, kof, wo);
      store_split(Bp + wo, pb[i]);
    }
    __syncthreads();
    if (s + 1 < S) {
      int ntn = (s+1) / NCH, chn = (s+1) % NCH;
      #pragma unroll
      for (int i = 0; i < 4; ++i) {
        int row, kof, wo;
        slot_decode(i, wave, lane, row, kof, wo);
        pb[i] = *(const f32x4*)&W[(long)((ntbase+ntn)*64 + row)*K + chn*64 + kof];
      }
    }
    mfma_step(Apl + ch*16384, Bp, lane, wr, wc, acc);
    if (ch == NCH - 1) {
      epilogue(acc, nullptr, nullptr, out, N, m0, (ntbase+nt)*64, wr, wc, lane, 4);
      #pragma unroll
      for (int i = 0; i < 2; ++i)
        #pragma unroll
        for (int j = 0; j < 2; ++j) acc[i][j] = (f32x4){0.f,0.f,0.f,0.f};
    }
  }
}

// ---------------- mgemm3 (imp-MLP tail only) ----------------
template<int K, int LN>
__global__ __launch_bounds__(256) void mgemm3_k(
    const float* __restrict__ A, const float* __restrict__ A2, int nsplit,
    const float* __restrict__ pe, int pe_mode,
    const float* __restrict__ g, const float* __restrict__ bb,
    const float* __restrict__ W, const float* __restrict__ bias,
    const float* __restrict__ res, float* __restrict__ out,
    int N, int act, int Mreal, int Mpad) {
  constexpr int NCH = K / 64;
  __shared__ char Apl[NCH * 16384];
  __shared__ char Bp[16384];
  int bid = blockIdx.x;
  int m = bid % Mpad, nt = bid / Mpad;
  if (m >= Mreal) return;
  int m0 = m*64, n0 = nt*64;
  int t = threadIdx.x, lane = t & 63, wave = t >> 6;
  int wr = wave >> 1, wc = wave & 1;
  const float* As = LN ? A2 : A;
  #pragma unroll
  for (int ch = 0; ch < NCH; ++ch)
    #pragma unroll
    for (int i = 0; i < 4; ++i) {
      int row, kof, wo;
      slot_decode(i, wave, lane, row, kof, wo);
      f32x4 av = *(const f32x4*)&As[(long)(m0 + row)*K + ch*64 + kof];
      store_split(Apl + ch*16384 + wo, av);
    }
  f32x4 pb[4];
  #pragma unroll
  for (int i = 0; i < 4; ++i) {
    int row, kof, wo;
    slot_decode(i, wave, lane, row, kof, wo);
    int br = n0 + row;
    pb[i] = (br < N) ? *(const f32x4*)&W[(long)br*K + kof] : (f32x4){0.f,0.f,0.f,0.f};
  }
  __syncthreads();
  f32x4 acc[2][2];
  #pragma unroll
  for (int i = 0; i < 2; ++i)
    #pragma unroll
    for (int j = 0; j < 2; ++j) acc[i][j] = (f32x4){0.f,0.f,0.f,0.f};
  for (int ch = 0; ch < NCH; ++ch) {
    #pragma unroll
    for (int i = 0; i < 4; ++i) {
      int row, kof, wo;
      slot_decode(i, wave, lane, row, kof, wo);
      store_split(Bp + wo, pb[i]);
    }
    __syncthreads();
    if (ch + 1 < NCH) {
      #pragma unroll
      for (int i = 0; i < 4; ++i) {
        int row, kof, wo;
        slot_decode(i, wave, lane, row, kof, wo);
        int br = n0 + row;
        pb[i] = (br < N) ? *(const f32x4*)&W[(long)br*K + (ch+1)*64 + kof]
                         : (f32x4){0.f,0.f,0.f,0.f};
      }
    }
    mfma_step(Apl + ch*16384, Bp, lane, wr, wc, acc);
    if (ch + 1 < NCH) __syncthreads();
  }
  epilogue(acc, bias, res, out, N, m0, n0, wr, wc, lane, act);
}

// ---------------- cgemm3: 3x3 conv as 9 shifted GEMMs, NTr n-tiles per block ----------------
__global__ __launch_bounds__(256) void cgemm3_k(
    const float* __restrict__ in, const float* __restrict__ W9, long wstride,
    const float* __restrict__ res, float* __restrict__ out, long ostride,
    int N, int NTr, int act, int Mreal, int Mpad) {
  __shared__ float halo[144 * 68];
  __shared__ char Ap[16384], Bp[16384];
  int bid = blockIdx.x;
  int m = bid % Mpad;
  if (m >= Mreal) return;
  int ly = blockIdx.y;
  W9  += (long)ly * wstride;
  out += (long)ly * ostride;
  int m0 = m*64;
  int a = m0 / 576, off = m0 % 576;
  int h_lo = off/24 - 1, h_hi = (off + 63)/24 + 1;
  int RH = h_hi - h_lo + 1;
  int t = threadIdx.x, lane = t & 63, wave = t >> 6;
  int wr = wave >> 1, wc = wave & 1;
  for (int sidx = t; sidx < RH*24*16; sidx += 256) {
    int tokr = sidx >> 4, c4 = (sidx & 15) << 2;
    int h = h_lo + tokr/24, w = tokr % 24;
    f32x4 v = {0.f,0.f,0.f,0.f};
    if ((unsigned)h < 24u) v = *(const f32x4*)&in[(long)(a*576 + h*24 + w)*64 + c4];
    *(f32x4*)&halo[tokr*68 + c4] = v;
  }
  f32x4 pb[4];
  #pragma unroll
  for (int i = 0; i < 4; ++i) {
    int row, kof, wo;
    slot_decode(i, wave, lane, row, kof, wo);
    pb[i] = (row < N) ? *(const f32x4*)&W9[(long)row*64 + kof] : (f32x4){0.f,0.f,0.f,0.f};
  }
  __syncthreads();
  int S = NTr * 9;
  f32x4 acc[2][2];
  #pragma unroll
  for (int i = 0; i < 2; ++i)
    #pragma unroll
    for (int j = 0; j < 2; ++j) acc[i][j] = (f32x4){0.f,0.f,0.f,0.f};
  for (int s = 0; s < S; ++s) {
    int nt = s / 9, ij = s % 9;
    int di = ij/3 - 1, dj = ij%3 - 1;
    #pragma unroll
    for (int i = 0; i < 4; ++i) {
      int row, kof, wo;
      slot_decode(i, wave, lane, row, kof, wo);
      int tok = off + row;
      int h2 = tok/24 + di, w2 = tok%24 + dj;
      f32x4 v = {0.f,0.f,0.f,0.f};
      if ((unsigned)h2 < 24u && (unsigned)w2 < 24u)
        v = *(const f32x4*)&halo[((h2 - h_lo)*24 + w2)*68 + kof];
      store_split(Ap + wo, v);
      store_split(Bp + wo, pb[i]);
    }
    __syncthreads();
    if (s + 1 < S) {
      int ntn = (s+1) / 9, ijn = (s+1) % 9;
      #pragma unroll
      for (int i = 0; i < 4; ++i) {
        int row, kof, wo;
        slot_decode(i, wave, lane, row, kof, wo);
        int br = ntn*64 + row;
        pb[i] = (br < N) ? *(const f32x4*)&W9[((long)ijn*N + br)*64 + kof]
                         : (f32x4){0.f,0.f,0.f,0.f};
      }
    }
    mfma_step(Ap, Bp, lane, wr, wc, acc);
    if (ij == 8) {
      epilogue(acc, nullptr, res, out, N, m0, nt*64, wr, wc, lane, act);
      #pragma unroll
      for (int i = 0; i < 2; ++i)
        #pragma unroll
        for (int j = 0; j < 2; ++j) acc[i][j] = (f32x4){0.f,0.f,0.f,0.f};
    }
    if (s + 1 < S) __syncthreads();
  }
}

// ---------------- ang_mega ----------------
__global__ __launch_bounds__(256) void ang_mega_k(
    const ushort* __restrict__ qkv, const float* __restrict__ Wout,
    const float* __restrict__ blkr, const float* __restrict__ g,
    const float* __restrict__ bb, float* __restrict__ atok, float* __restrict__ tnf) {
  int hw = blockIdx.x;
  __shared__ float lq[25*192];
  __shared__ float lao[25*64];
  __shared__ float po[25*68];
  __shared__ float wout[64*65];
  __shared__ float st[25][2];
  int t = threadIdx.x;
  for (int idx = t; idx < 600; idx += 256) {
    int a3 = idx / 24, c8 = (idx % 24) * 8;
    s16x8 r = *(const s16x8*)&qkv[(long)(a3*576 + hw)*192 + c8];
    #pragma unroll
    for (int e = 0; e < 8; ++e) lq[a3*192 + c8 + e] = bf2f((ushort)r[e]);
  }
  for (int idx = t; idx < 1024; idx += 256) {
    f32x4 wv = *(const f32x4*)&Wout[idx*4];
    int c = (idx*4) >> 6, d = (idx*4) & 63;
    #pragma unroll
    for (int e = 0; e < 4; ++e) wout[c*65 + d + e] = wv[e];
  }
  __syncthreads();
  if (t < 200) {
    int l = t / 8, head = t & 7;
    const float* q = lq + l*192 + head*8;
    float s[25]; float mx = -1e30f;
    #pragma unroll
    for (int mm = 0; mm < 25; ++mm) {
      const float* kk = lq + mm*192 + 64 + head*8;
      float acc = 0.f;
      #pragma unroll
      for (int d = 0; d < 8; ++d) acc = fmaf(q[d], kk[d], acc);
      acc *= 0.3535533905932738f;
      s[mm] = acc; mx = fmaxf(mx, acc);
    }
    float sum = 0.f;
    #pragma unroll
    for (int mm = 0; mm < 25; ++mm) { s[mm] = expf(s[mm] - mx); sum += s[mm]; }
    float inv = 1.f / sum;
    #pragma unroll
    for (int d = 0; d < 8; ++d) {
      float acc = 0.f;
      #pragma unroll
      for (int mm = 0; mm < 25; ++mm) acc = fmaf(s[mm], lq[mm*192 + 128 + head*8 + d], acc);
      lao[l*64 + head*8 + d] = acc * inv;
    }
  }
  __syncthreads();
  for (int idx = t; idx < 1600; idx += 256) {
    int tok = idx >> 6, c = idx & 63;
    const float* ar = &lao[tok*64];
    const float* wr = &wout[c*65];
    float accp = 0.f;
    #pragma unroll 16
    for (int d = 0; d < 64; ++d) accp = fmaf(ar[d], wr[d], accp);
    po[tok*68 + c] = accp + blkr[(long)(tok*576 + hw)*64 + c];
  }
  __syncthreads();
  if (t < 25) {
    float s = 0.f, q = 0.f;
    for (int c = 0; c < 64; ++c) { float x = po[t*68 + c]; s += x; q = fmaf(x, x, q); }
    float mean = s / 64.f, var = q / 64.f - mean*mean;
    st[t][0] = mean; st[t][1] = rsqrtf(var + 1e-5f);
  }
  __syncthreads();
  for (int idx = t; idx < 1600; idx += 256) {
    int tok = idx >> 6, c = idx & 63;
    float x = po[tok*68 + c];
    long gidx = (long)(tok*576 + hw)*64 + c;
    atok[gidx] = x;
    tnf[gidx] = (x - st[tok][0]) * st[tok][1] * g[c] + bb[c];
  }
}

// ---------------- ffn_ang ----------------
__global__ __launch_bounds__(256) void ffn_ang_k(
    const float* __restrict__ tnf, const float* __restrict__ w1,
    const float* __restrict__ w2, float* __restrict__ atok,
    int Mreal, int Mpad) {
  __shared__ char Ap[16384], Bp[16384], Hp[2][16384];
  int bid = blockIdx.x;
  int m = bid % Mpad;
  if (m >= Mreal) return;
  int m0 = m*64;
  int t = threadIdx.x, lane = t & 63, wave = t >> 6;
  int wr = wave >> 1, wc = wave & 1;
  #pragma unroll
  for (int i = 0; i < 4; ++i) {
    int row, kof, wo;
    slot_decode(i, wave, lane, row, kof, wo);
    f32x4 av = *(const f32x4*)&tnf[(long)(m0 + row)*64 + kof];
    store_split(Ap + wo, av);
  }
  f32x4 pb[4];
  #pragma unroll
  for (int i = 0; i < 4; ++i) {
    int row, kof, wo;
    slot_decode(i, wave, lane, row, kof, wo);
    pb[i] = *(const f32x4*)&w1[(long)row*64 + kof];
  }
  __syncthreads();
  for (int nt = 0; nt < 2; ++nt) {
    #pragma unroll
    for (int i = 0; i < 4; ++i) {
      int row, kof, wo;
      slot_decode(i, wave, lane, row, kof, wo);
      store_split(Bp + wo, pb[i]);
    }
    __syncthreads();
    #pragma unroll
    for (int i = 0; i < 4; ++i) {
      int row, kof, wo;
      slot_decode(i, wave, lane, row, kof, wo);
      pb[i] = (nt == 0) ? *(const f32x4*)&w1[(long)(64 + row)*64 + kof]
                        : *(const f32x4*)&w2[(long)row*128 + kof];
    }
    f32x4 acc[2][2];
    #pragma unroll
    for (int i = 0; i < 2; ++i)
      #pragma unroll
      for (int j = 0; j < 2; ++j) acc[i][j] = (f32x4){0.f,0.f,0.f,0.f};
    mfma_step(Ap, Bp, lane, wr, wc, acc);
    #pragma unroll
    for (int jj = 0; jj < 2; ++jj)
      #pragma unroll
      for (int ii = 0; ii < 2; ++ii)
        #pragma unroll
        for (int r = 0; r < 4; ++r) {
          int rr = wr*32 + ii*16 + ((lane >> 4) << 2) + r;
          int cc = wc*32 + jj*16 + (lane & 15);
          scatter_split(Hp[nt], rr, cc, fmaxf(acc[ii][jj][r], 0.f));
        }
    __syncthreads();
  }
  f32x4 acc2[2][2];
  #pragma unroll
  for (int i = 0; i < 2; ++i)
    #pragma unroll
    for (int j = 0; j < 2; ++j) acc2[i][j] = (f32x4){0.f,0.f,0.f,0.f};
  for (int ch = 0; ch < 2; ++ch) {
    #pragma unroll
    for (int i = 0; i < 4; ++i) {
      int row, kof, wo;
      slot_decode(i, wave, lane, row, kof, wo);
      store_split(Bp + wo, pb[i]);
    }
    __syncthreads();
    if (ch == 0) {
      #pragma unroll
      for (int i = 0; i < 4; ++i) {
        int row, kof, wo;
        slot_decode(i, wave, lane, row, kof, wo);
        pb[i] = *(const f32x4*)&w2[(long)row*128 + 64 + kof];
      }
    }
    mfma_step(Hp[ch], Bp, lane, wr, wc, acc2);
    if (ch == 0) __syncthreads();
  }
  epilogue(acc2, nullptr, atok, atok, 64, m0, 0, wr, wc, lane, 0);
}

// ---------------- megaspa (512 threads, direct-load attention, batched B stages) ----------------
__global__ __launch_bounds__(512) void megaspa_k(
    const ushort* __restrict__ qkv, const float* __restrict__ stok,
    const float* __restrict__ wout, const float* __restrict__ g,
    const float* __restrict__ bb, const float* __restrict__ w1,
    const float* __restrict__ w2, const float* __restrict__ wlin,
    float* __restrict__ outb, int Mreal, int Mpad) {
  __shared__ char Aop[32768];
  __shared__ char SCR[65536];
  __shared__ float Rf[64*132];
  __shared__ float st[64][2];
  int bid = blockIdx.x;
  int m = bid % Mpad;
  if (m >= Mreal) return;
  int m0 = m*64;
  int t = threadIdx.x, lane = t & 63, wave = t >> 6;
  int wgrp = wave >> 2, w4 = wave & 3;
  int wr = w4 >> 1, wc = w4 & 1;
  char* Bp  = SCR + wgrp*16384;
  char* Hp0 = SCR + 32768;
  char* Hp1 = SCR + 49152;

  // ---- Phase 0: stage stok residual into Rf; prefetch phase-2 wout tiles ----
  for (int idx = t; idx < 2048; idx += 512) {
    int row = idx >> 5, c4 = (idx & 31) << 2;
    *(f32x4*)&Rf[row*132 + c4] = *(const f32x4*)&stok[(long)(m0 + row)*128 + c4];
  }
  f32x4 pw[2][4];
  #pragma unroll
  for (int ch = 0; ch < 2; ++ch)
    #pragma unroll
    for (int i = 0; i < 4; ++i) {
      int row, kof, wo;
      slot_decode(i, w4, lane, row, kof, wo);
      pw[ch][i] = *(const f32x4*)&wout[(long)(wgrp*64 + row)*128 + ch*64 + kof];
    }

  // ---- Phase 1: windowed attention (1 task/thread), batched clamped global loads ----
  {
    int rr1 = t >> 3, head = t & 7;
    int x = m0 + rr1;
    int hw = x % 576, h = hw / 24, w = hw % 24;
    float qr[16];
    ld_bf16x16(qkv + (long)x*384 + head*16, qr);
    float s[25]; float mx = -1e30f;
    #pragma unroll
    for (int ro = 0; ro < 5; ++ro) {
      int h2 = h + ro - 2;
      s16x8 k0[5], k1[5];
      #pragma unroll
      for (int co = 0; co < 5; ++co) {
        int xt = x + (ro - 2)*24 + (co - 2);
        xt = min(max(xt, 0), 14399);
        const ushort* kp = qkv + (long)xt*384 + 128 + head*16;
        k0[co] = *(const s16x8*)kp;
        k1[co] = *(const s16x8*)(kp + 8);
      }
      #pragma unroll
      for (int co = 0; co < 5; ++co) {
        int w2c = w + co - 2;
        float sc = -1e30f;
        if (h2 >= 0 && h2 < 24 && w2c >= 0 && w2c < 24) {
          sc = 0.f;
          #pragma unroll
          for (int d = 0; d < 8; ++d) sc = fmaf(qr[d], bf2f((ushort)k0[co][d]), sc);
          #pragma unroll
          for (int d = 0; d < 8; ++d) sc = fmaf(qr[8+d], bf2f((ushort)k1[co][d]), sc);
          sc *= 0.25f;
        }
        s[ro*5 + co] = sc; mx = fmaxf(mx, sc);
      }
    }
    float sum = 0.f;
    #pragma unroll
    for (int i = 0; i < 25; ++i) {
      float e = (s[i] > -1e29f) ? expf(s[i] - mx) : 0.f;
      s[i] = e; sum += e;
    }
    float inv = 1.f / sum;
    float acc[16];
    #pragma unroll
    for (int d = 0; d < 16; ++d) acc[d] = 0.f;
    #pragma unroll
    for (int ro = 0; ro < 5; ++ro) {
      s16x8 v0[5], v1[5];
      #pragma unroll
      for (int co = 0; co < 5; ++co) {
        int xt = x + (ro - 2)*24 + (co - 2);
        xt = min(max(xt, 0), 14399);
        const ushort* vp = qkv + (long)xt*384 + 256 + head*16;
        v0[co] = *(const s16x8*)vp;
        v1[co] = *(const s16x8*)(vp + 8);
      }
      #pragma unroll
      for (int co = 0; co < 5; ++co) {
        float sv = s[ro*5 + co];
        #pragma unroll
        for (int d = 0; d < 8; ++d) acc[d] = fmaf(sv, bf2f((ushort)v0[co][d]), acc[d]);
        #pragma unroll
        for (int d = 0; d < 8; ++d) acc[8+d] = fmaf(sv, bf2f((ushort)v1[co][d]), acc[8+d]);
      }
    }
    #pragma unroll
    for (int d = 0; d < 16; ++d) {
      int cc = head*16 + d;
      scatter_split(Aop + (cc >> 6)*16384, rr1, cc & 63, acc[d] * inv);
    }
  }

  // ---- Phase 2: proj + residual -> Rf (all 4 B tiles staged, single barrier) ----
  {
    #pragma unroll
    for (int ch = 0; ch < 2; ++ch)
      #pragma unroll
      for (int i = 0; i < 4; ++i) {
        int row, kof, wo;
        slot_decode(i, w4, lane, row, kof, wo);
        store_split(SCR + (wgrp*2 + ch)*16384 + wo, pw[ch][i]);
      }
    __syncthreads();
    int nt = wgrp;
    f32x4 acc[2][2];
    #pragma unroll
    for (int i = 0; i < 2; ++i)
      #pragma unroll
      for (int j = 0; j < 2; ++j) acc[i][j] = (f32x4){0.f,0.f,0.f,0.f};
    for (int ch = 0; ch < 2; ++ch)
      mfma_step(Aop + ch*16384, SCR + (wgrp*2 + ch)*16384, lane, wr, wc, acc);
    int colb = nt*64 + wc*32 + (lane & 15);
    int rowb = wr*32 + ((lane >> 4) << 2);
    #pragma unroll
    for (int j = 0; j < 2; ++j)
      #pragma unroll
      for (int i = 0; i < 2; ++i)
        #pragma unroll
        for (int r = 0; r < 4; ++r) {
          int rr = rowb + i*16 + r, cc = colb + j*16;
          Rf[rr*132 + cc] += acc[i][j][r];
        }
  }
  __syncthreads();

  // ---- Phase 3: LN (8 threads/row over padded Rf) -> normed planes (ch = wgrp) ----
  {
    int row = t >> 3, q8 = t & 7;
    const float* yr = &Rf[row*132 + q8*16];
    float sm = 0.f, sq = 0.f;
    #pragma unroll
    for (int j2 = 0; j2 < 16; ++j2) { float xv = yr[j2]; sm += xv; sq = fmaf(xv, xv, sq); }
    sm += __shfl_xor(sm, 1, 64); sq += __shfl_xor(sq, 1, 64);
    sm += __shfl_xor(sm, 2, 64); sq += __shfl_xor(sq, 2, 64);
    sm += __shfl_xor(sm, 4, 64); sq += __shfl_xor(sq, 4, 64);
    if (q8 == 0) {
      float mean = sm / 128.f, var = sq / 128.f - mean*mean;
      st[row][0] = mean; st[row][1] = rsqrtf(var + 1e-5f);
    }
  }
  __syncthreads();
  {
    int ch = wgrp;
    #pragma unroll
    for (int i = 0; i < 4; ++i) {
      int row, kof, wo;
      slot_decode(i, w4, lane, row, kof, wo);
      int gk = ch*64 + kof;
      f32x4 xv = *(const f32x4*)&Rf[row*132 + gk];
      float mean = st[row][0], rstd = st[row][1];
      f32x4 gv = *(const f32x4*)&g[gk];
      f32x4 bv = *(const f32x4*)&bb[gk];
      f32x4 nv;
      #pragma unroll
      for (int e = 0; e < 4; ++e) nv[e] = (xv[e] - mean)*rstd*gv[e] + bv[e];
      store_split(Aop + ch*16384 + wo, nv);
    }
  }

  // ---- Phase 4+5: FFN1/FFN2 interleaved, 2 rounds; acc2 persists ----
  f32x4 acc2[2][2];
  #pragma unroll
  for (int i = 0; i < 2; ++i)
    #pragma unroll
    for (int j = 0; j < 2; ++j) acc2[i][j] = (f32x4){0.f,0.f,0.f,0.f};
  for (int r = 0; r < 2; ++r) {
    int nt = 2*r + wgrp;
    f32x4 accH[2][2];
    #pragma unroll
    for (int i = 0; i < 2; ++i)
      #pragma unroll
      for (int j = 0; j < 2; ++j) accH[i][j] = (f32x4){0.f,0.f,0.f,0.f};
    for (int ch = 0; ch < 2; ++ch) {
      __syncthreads();
      #pragma unroll
      for (int i = 0; i < 4; ++i) {
        int row, kof, wo;
        slot_decode(i, w4, lane, row, kof, wo);
        f32x4 bv = *(const f32x4*)&w1[(long)(nt*64 + row)*128 + ch*64 + kof];
        store_split(Bp + wo, bv);
      }
      __syncthreads();
      mfma_step(Aop + ch*16384, Bp, lane, wr, wc, accH);
    }
    char* Hpw = wgrp ? Hp1 : Hp0;
    #pragma unroll
    for (int jj = 0; jj < 2; ++jj)
      #pragma unroll
      for (int ii = 0; ii < 2; ++ii)
        #pragma unroll
        for (int rx = 0; rx < 4; ++rx) {
          int rr = wr*32 + ii*16 + ((lane >> 4) << 2) + rx;
          int cc = wc*32 + jj*16 + (lane & 15);
          scatter_split(Hpw, rr, cc, fmaxf(accH[ii][jj][rx], 0.f));
        }
    for (int q = 0; q < 2; ++q) {
      __syncthreads();
      #pragma unroll
      for (int i = 0; i < 4; ++i) {
        int row, kof, wo;
        slot_decode(i, w4, lane, row, kof, wo);
        f32x4 bv = *(const f32x4*)&w2[(long)(wgrp*64 + row)*256 + (2*r + q)*64 + kof];
        store_split(Bp + wo, bv);
      }
      __syncthreads();
      mfma_step(q ? Hp1 : Hp0, Bp, lane, wr, wc, acc2);
    }
  }
  {
    int colb = wc*32 + (lane & 15);
    int rowb = wr*32 + ((lane >> 4) << 2);
    #pragma unroll
    for (int jj = 0; jj < 2; ++jj)
      #pragma unroll
      for (int ii = 0; ii < 2; ++ii)
        #pragma unroll
        for (int rx = 0; rx < 4; ++rx) {
          int rr = rowb + ii*16 + rx;
          int cc = colb + jj*16;
          scatter_split(Aop + wgrp*16384, rr, cc,
                        acc2[ii][jj][rx] + Rf[rr*132 + wgrp*64 + cc]);
        }
  }

  // ---- Phase 6: spa_lin -> blk (tiles staged by ch==wgrp, batched barriers) ----
  __syncthreads();
  {
    int ch = wgrp;
    #pragma unroll
    for (int i = 0; i < 4; ++i) {
      int row, kof, wo;
      slot_decode(i, w4, lane, row, kof, wo);
      f32x4 bv = *(const f32x4*)&wlin[(long)row*128 + ch*64 + kof];
      store_split(SCR + ch*16384 + wo, bv);
    }
  }
  __syncthreads();
  if (wgrp == 0) {
    f32x4 acc3[2][2];
    #pragma unroll
    for (int i = 0; i < 2; ++i)
      #pragma unroll
      for (int j = 0; j < 2; ++j) acc3[i][j] = (f32x4){0.f,0.f,0.f,0.f};
    for (int ch = 0; ch < 2; ++ch)
      mfma_step(Aop + ch*16384, SCR + ch*16384, lane, wr, wc, acc3);
    epilogue(acc3, nullptr, nullptr, outb, 64, m0, 0, wr, wc, lane, 0);
  }
}

// ---------------- zgemm3 ----------------
__global__ __launch_bounds__(256) void zgemm3_k(
    const float* __restrict__ buf, const float* __restrict__ blk,
    const float* __restrict__ W0, float* __restrict__ Zp) {
  __shared__ char Ap[16384], Bp[16384];
  int bid = blockIdx.x;
  int m = bid % 9;
  int nz = bid / 9;
  int n = nz % 5, z = nz / 5;
  int m0 = m*64, n0 = n*64;
  int t = threadIdx.x, lane = t & 63, wave = t >> 6;
  int wr = wave >> 1, wc = wave & 1;
  f32x4 pa[4], pb[4];
  #pragma unroll
  for (int i = 0; i < 4; ++i) {
    int row, kof, wo;
    slot_decode(i, wave, lane, row, kof, wo);
    long tok = (long)(z*5)*576 + m0 + row;
    pa[i] = *(const f32x4*)&buf[tok*64 + kof];
    pa[i] += *(const f32x4*)&blk[tok*64 + kof];
    pb[i] = *(const f32x4*)&W0[(long)(n0 + row)*1652 + (z*5)*64 + kof];
  }
  f32x4 acc[2][2];
  #pragma unroll
  for (int i = 0; i < 2; ++i)
    #pragma unroll
    for (int j = 0; j < 2; ++j) acc[i][j] = (f32x4){0.f,0.f,0.f,0.f};
  for (int q = 0; q < 5; ++q) {
    #pragma unroll
    for (int i = 0; i < 4; ++i) {
      int row, kof, wo;
      slot_decode(i, wave, lane, row, kof, wo);
      store_split(Ap + wo, pa[i]);
      store_split(Bp + wo, pb[i]);
    }
    __syncthreads();
    if (q < 4) {
      #pragma unroll
      for (int i = 0; i < 4; ++i) {
        int row, kof, wo;
        slot_decode(i, wave, lane, row, kof, wo);
        long tok = (long)(z*5 + q + 1)*576 + m0 + row;
        pa[i] = *(const f32x4*)&buf[tok*64 + kof];
        pa[i] += *(const f32x4*)&blk[tok*64 + kof];
        pb[i] = *(const f32x4*)&W0[(long)(n0 + row)*1652 + (z*5 + q + 1)*64 + kof];
      }
    }
    mfma_step(Ap, Bp, lane, wr, wc, acc);
    if (q < 4) __syncthreads();
  }
  epilogue(acc, nullptr, nullptr, Zp + (long)z*184320, 320, m0, n0, wr, wc, lane, 0);
}

// ---------------- combine ----------------
__global__ void combine_k(const float* __restrict__ Zp, const float* __restrict__ cav,
                          const float* __restrict__ coord, float* __restrict__ h0out) {
  int gidx = blockIdx.x * 256 + threadIdx.x;
  if (gidx >= 2304 * 320) return;
  int p = gidx / 320, o = gidx % 320;
  int hh = p / 48, ww = p % 48;
  float sh = hh * 0.5f - 0.25f, sw = ww * 0.5f - 0.25f;
  int h0i = (int)floorf(sh); float fh = sh - h0i;
  int w0i = (int)floorf(sw); float fw = sw - w0i;
  int h0c = max(h0i, 0), h1c = min(h0i + 1, 23);
  int w0c = max(w0i, 0), w1c = min(w0i + 1, 23);
  int i00 = (h0c*24 + w0c)*320 + o, i01 = (h0c*24 + w1c)*320 + o;
  int i10 = (h1c*24 + w0c)*320 + o, i11 = (h1c*24 + w1c)*320 + o;
  float z00 = 0.f, z01 = 0.f, z10 = 0.f, z11 = 0.f;
  #pragma unroll
  for (int z = 0; z < 5; ++z) {
    const float* Zz = Zp + (long)z*184320;
    z00 += Zz[i00]; z01 += Zz[i01]; z10 += Zz[i10]; z11 += Zz[i11];
  }
  float v = (1.f-fh)*((1.f-fw)*z00 + fw*z01) + fh*((1.f-fw)*z10 + fw*z11);
  #pragma unroll
  for (int d = 0; d < 2; ++d) {
    float co = coord[p*2 + d];
    float cc = fminf(fmaxf(co + 1e-6f, -1.f + 1e-6f), 1.f - 1e-6f);
    float ix = rintf(((cc + 1.f)*24.f - 1.f)*0.5f);
    ix = fminf(fmaxf(ix, 0.f), 23.f);
    float q = -1.f + (2.f*ix + 1.f)/24.f;
    v = fmaf((co - q)*24.f, cav[320*(d+1) + o], v);
  }
  h0out[gidx] = fmaxf(v + cav[o], 0.f);
}

// ---------------- setup ----------------
__device__ inline float pe_val(int pos, int c) {
  int j = c & 31;
  float freq = powf(10000.f, -2.f * (float)j / 64.f);
  float arg = (float)pos * freq;
  return (c < 32) ? sinf(arg) : cosf(arg);
}

__global__ void setup_k(const float* __restrict__ lr, const float* __restrict__ convi_w,
                        const float* __restrict__ spa_mlp,
                        const float* __restrict__ imp_w0, const float* __restrict__ imp_b0,
                        float* pe25, float* spa_pe, float* X, float* w9c, float* w9s,
                        float* cav) {
  int g = blockIdx.x * 256 + threadIdx.x;
  if (g < 1600) { pe25[g] = pe_val(g >> 6, g & 63); return; }
  g -= 1600;
  if (g < 36864) {
    int hw = g >> 6, c = g & 63; int h = hw / 24, w = hw % 24;
    spa_pe[g] = 0.5f * (pe_val(h, c) + pe_val(w, c)); return;
  }
  g -= 36864;
  if (g < 14400) {
    int aa = g / 576, hw = g % 576, h = hw / 24, w = hw % 24;
    X[g] = lr[((aa/5)*24 + h)*120 + (aa%5)*24 + w]; return;
  }
  g -= 14400;
  if (g < 110592) {
    int cv = g / 36864, rem = g % 36864;
    int ij = rem / 4096, oc = rem % 4096;
    int o = oc >> 6, c = oc & 63;
    w9c[g] = convi_w[((long)(cv*64 + o)*64 + c)*9 + ij]; return;
  }
  g -= 110592;
  if (g < 294912) {
    int l = g / 73728, rem = g % 73728;
    int ij = rem / 8192, oc = rem % 8192;
    int o = oc >> 6, c = oc & 63;
    w9s[g] = spa_mlp[((long)(l*128 + o))*576 + c*9 + ij]; return;
  }
  g -= 294912;
  if (g < 320) {
    int o = g;
    float s = imp_b0[o];
    #pragma unroll
    for (int idx = 0; idx < 50; ++idx) {
      int pair = idx >> 1;
      float cvv = 0.5f + (float)((idx & 1) ? pair % 5 : pair / 5);
      s = fmaf(cvv, imp_w0[(long)o*1652 + 1602 + idx], s);
    }
    cav[o] = s;
    cav[320 + o] = imp_w0[(long)o*1652 + 1600];
    cav[640 + o] = imp_w0[(long)o*1652 + 1601];
  }
}

// ---------------- conv0 ----------------
__global__ void conv0_k(const float* __restrict__ X, const float* __restrict__ W,
                        float* __restrict__ out) {
  int sp = threadIdx.x >> 6, lane = threadIdx.x & 63;
  int strip = blockIdx.x * 4 + sp;
  int a = strip / 48, r = strip % 48, h = r >> 1, w0 = (r & 1) * 12;
  __shared__ float patch[4][3][16];
  if (lane < 42) {
    int i = lane / 14, col = lane % 14;
    int h2 = h + i - 1, w2 = w0 + col - 1;
    float v = 0.f;
    if ((unsigned)h2 < 24u && (unsigned)w2 < 24u) v = X[a*576 + h2*24 + w2];
    patch[sp][i][col] = v;
  }
  __syncthreads();
  float wv[9];
  #pragma unroll
  for (int q = 0; q < 9; ++q) wv[q] = W[lane*9 + q];
  #pragma unroll
  for (int p = 0; p < 12; ++p) {
    float acc = 0.f;
    #pragma unroll
    for (int i = 0; i < 3; ++i)
      #pragma unroll
      for (int j = 0; j < 3; ++j)
        acc = fmaf(patch[sp][i][p + j], wv[i*3 + j], acc);
    out[(long)(a*576 + h*24 + w0 + p)*64 + lane] = acc;
  }
}

// ---------------- host launch ----------------
extern "C" void kernel_launch(void* const* d_in, const int* in_sizes, int n_in,
                              void* d_out, int out_size, void* d_ws, size_t ws_size,
                              hipStream_t stream) {
  (void)in_sizes; (void)n_in; (void)out_size;
  if (ws_size < (size_t)WS_FLOATS * 4) return;
  float* ws = (float*)d_ws;

  const float* lr       = (const float*)d_in[0];
  const float* coord    = (const float*)d_in[1];
  const float* conv0_w  = (const float*)d_in[2];
  const float* convi_w  = (const float*)d_in[3];
  const float* ang_ln_g = (const float*)d_in[4];
  const float* ang_ln_b = (const float*)d_in[5];
  const float* ang_in   = (const float*)d_in[6];
  const float* ang_out  = (const float*)d_in[7];
  const float* ang_ff_g = (const float*)d_in[8];
  const float* ang_ff_b = (const float*)d_in[9];
  const float* ang_w1   = (const float*)d_in[10];
  const float* ang_w2   = (const float*)d_in[11];
  const float* spa_mlp  = (const float*)d_in[12];
  const float* spa_ln_g = (const float*)d_in[13];
  const float* spa_ln_b = (const float*)d_in[14];
  const float* spa_in   = (const float*)d_in[15];
  const float* spa_out  = (const float*)d_in[16];
  const float* spa_ff_g = (const float*)d_in[17];
  const float* spa_ff_b = (const float*)d_in[18];
  const float* spa_w1   = (const float*)d_in[19];
  const float* spa_w2   = (const float*)d_in[20];
  const float* spa_lin  = (const float*)d_in[21];
  const float* imp_w0   = (const float*)d_in[22];
  const float* imp_b0   = (const float*)d_in[23];
  const float* imp_w1   = (const float*)d_in[24];
  const float* imp_b1   = (const float*)d_in[25];
  const float* imp_w2   = (const float*)d_in[26];
  const float* imp_b2   = (const float*)d_in[27];

  float* pe25 = ws + PE25_;  float* spa_pe = ws + SPAPE_;  float* X = ws + X_;
  float* cav = ws + CAV_;    float* petok = ws + PETOK_;
  float* w9c = ws + W9C_;    float* w9s = ws + W9S_;
  float* buf = ws + BUF_;    float* blk = ws + BLK_;      float* atok = ws + ATOK_;
  float* tnf = ws + TNF_;    float* stok = ws + STOK_;
  float* qkvf = ws + QKV_;   ushort* qkvh = (ushort*)(ws + QKV_);
  float* t0 = ws + T0_;      float* t1 = ws + T1_;
  float* Zp = ws + ZP_;      float* h0 = ws + H0_;        float* h1 = ws + H1_;

  setup_k<<<1792, 256, 0, stream>>>(lr, convi_w, spa_mlp, imp_w0, imp_b0,
                                    pe25, spa_pe, X, w9c, w9s, cav);
  conv0_k<<<300, 256, 0, stream>>>(X, conv0_w, buf);
  cgemm3_k<<<dim3(232,1), 256, 0, stream>>>(buf, w9c,         0, nullptr, t0,  0, 64, 1, 2, 225, 232);
  cgemm3_k<<<dim3(232,1), 256, 0, stream>>>(t0,  w9c + 36864, 0, nullptr, t1,  0, 64, 1, 2, 225, 232);
  cgemm3_k<<<dim3(232,1), 256, 0, stream>>>(t1,  w9c + 73728, 0, buf,     buf, 0, 64, 1, 2, 225, 232);
  cgemm3_k<<<dim3(16, 4), 256, 0, stream>>>(spa_pe, w9s, 73728, nullptr, petok, 73728,
                                            128, 2, 0, 9, 16);

  for (int l = 0; l < 4; ++l) {
    const float* blkr = (l == 0) ? buf : blk;
    // ---- AngTrans ----
    qkvg_k<64><<<464, 256, 0, stream>>>(blkr, pe25, 0,
        ang_ln_g + l*64, ang_ln_b + l*64, ang_in + l*192*64, qkvf,
        2, 1, 192, 225, 232);
    ang_mega_k<<<576, 256, 0, stream>>>(qkvh, ang_out + l*64*64, blkr,
        ang_ff_g + l*64, ang_ff_b + l*64, atok, tnf);
    ffn_ang_k<<<232, 256, 0, stream>>>(tnf, ang_w1 + l*128*64, ang_w2 + l*64*128,
        atok, 225, 232);
    // ---- SpaTrans ----
    cgemm3_k<<<dim3(232,1), 256, 0, stream>>>(atok, w9s + l*73728, 0, nullptr, stok, 0,
        128, 2, 0, 225, 232);
    qkvg_k<128><<<464, 256, 0, stream>>>(stok, petok + l*73728, 1,
        spa_ln_g + l*128, spa_ln_b + l*128, spa_in + l*384*128, qkvf,
        4, 2, 384, 225, 232);
    megaspa_k<<<232, 512, 0, stream>>>(qkvh, stok, spa_out + l*128*128,
        spa_ff_g + l*128, spa_ff_b + l*128, spa_w1 + l*256*128, spa_w2 + l*128*256,
        spa_lin + l*64*128, blk, 225, 232);
  }

  zgemm3_k<<<225, 256, 0, stream>>>(buf, blk, imp_w0, Zp);
  combine_k<<<2880, 256, 0, stream>>>(Zp, cav, coord, h0);
  mgemm3_k<320,0><<<200, 256, 0, stream>>>(h0, h0, 0, nullptr, -1, nullptr, nullptr,
      imp_w1, imp_b1, nullptr, h1, 320, 1, 36, 40);
  mgemm3_k<320,0><<<80, 256, 0, stream>>>(h1, h1, 0, nullptr, -1, nullptr, nullptr,
      imp_w2, imp_b2, nullptr, (float*)d_out, 75, 3, 36, 40);
}

// Round 16
// 553.699 us; speedup vs baseline: 1.1430x; 1.1430x over previous
//
#include <hip/hip_runtime.h>
#include <math.h>

typedef short  s16x4 __attribute__((ext_vector_type(4)));
typedef short  s16x8 __attribute__((ext_vector_type(8)));
typedef float  f32x4 __attribute__((ext_vector_type(4)));

// ---------------- workspace float offsets ----------------
static const size_t PE25_  = 0;
static const size_t SPAPE_ = 2048;
static const size_t X_     = 38912;
static const size_t CAV_   = 53312;
static const size_t PETOK_ = 54272;
static const size_t W9C_   = 349184;
static const size_t W9S_   = 459776;
static const size_t BUF_   = 754688;
static const size_t BLK_   = 1676288;
static const size_t ATOK_  = 2597888;
static const size_t TNF_   = 3519488;
static const size_t STOK_  = 4441088;
static const size_t STOK2_ = 6284288;
static const size_t QKV_   = 9970688;    // bf16 [14400][384]
static const size_t WS_FLOATS = 15500288;
static const size_t T0_ = QKV_ + 2764800;
static const size_t T1_ = T0_ + 921600;
static const size_t ZP_ = QKV_;
static const size_t H0_ = STOK_;
static const size_t H1_ = STOK2_;

// ---------------- bf16 split helpers ----------------
__device__ inline ushort f2bf(float x) {
  unsigned u = __float_as_uint(x);
  u += 0x7fffu + ((u >> 16) & 1u);
  return (ushort)(u >> 16);
}
__device__ inline float bf2f(ushort h) { return __uint_as_float(((unsigned)h) << 16); }

__device__ inline void store_split(char* p, f32x4 v) {
  s16x4 hi, lo;
  #pragma unroll
  for (int e = 0; e < 4; ++e) {
    float x = v[e];
    ushort h = f2bf(x);
    ushort l = f2bf(x - bf2f(h));
    hi[e] = (short)h; lo[e] = (short)l;
  }
  *(s16x4*)p = hi;
  *(s16x4*)(p + 1024) = lo;
}

__device__ inline void scatter_split(char* base, int rr, int c6, float v) {
  ushort hi = f2bf(v);
  ushort lo = f2bf(v - bf2f(hi));
  int ks = c6 >> 5, kh = (c6 >> 4) & 1, k4 = (c6 >> 2) & 3;
  int lane2 = (k4 >> 1)*32 + ((rr & 15) << 1) + (k4 & 1);
  int byt = (((rr >> 4)*2 + ks) << 11) + (kh << 9) + (lane2 << 3) + (c6 & 3)*2;
  *(ushort*)(base + byt) = hi;
  *(ushort*)(base + byt + 1024) = lo;
}

__device__ inline void ld_bf16x16(const ushort* p, float* dst) {
  s16x8 a = *(const s16x8*)p;
  s16x8 b = *(const s16x8*)(p + 8);
  #pragma unroll
  for (int e = 0; e < 8; ++e) { dst[e] = bf2f((ushort)a[e]); dst[8 + e] = bf2f((ushort)b[e]); }
}

__device__ inline void slot_decode(int i, int wave, int lane,
                                   int& row, int& kof, int& wo) {
  int idx = (i << 2) + wave;
  int msub = idx >> 2, ks = (idx >> 1) & 1, kh = idx & 1;
  int rsub = (lane >> 1) & 15;
  int ksub = ((lane >> 5) << 3) + ((lane & 1) << 2);
  row = (msub << 4) + rsub;
  kof = (ks << 5) + (kh << 4) + ksub;
  wo = ((msub * 2 + ks) << 11) + (kh << 9) + (lane << 3);
}

__device__ inline void mfma_step(const char* ldsA, const char* ldsB, int lane,
                                 int wr, int wc, f32x4 acc[2][2]) {
  #pragma unroll
  for (int ks = 0; ks < 2; ++ks) {
    s16x8 ah[2], al[2], bh[2], bl[2];
    #pragma unroll
    for (int i = 0; i < 2; ++i) {
      const char* pa = ldsA + (((wr*2 + i)*2 + ks) << 11) + (lane << 4);
      ah[i] = *(const s16x8*)pa;
      al[i] = *(const s16x8*)(pa + 1024);
      const char* pb = ldsB + (((wc*2 + i)*2 + ks) << 11) + (lane << 4);
      bh[i] = *(const s16x8*)pb;
      bl[i] = *(const s16x8*)(pb + 1024);
    }
    #pragma unroll
    for (int i = 0; i < 2; ++i) {
      #pragma unroll
      for (int j = 0; j < 2; ++j) {
        acc[i][j] = __builtin_amdgcn_mfma_f32_16x16x32_bf16(ah[i], bh[j], acc[i][j], 0, 0, 0);
        acc[i][j] = __builtin_amdgcn_mfma_f32_16x16x32_bf16(ah[i], bl[j], acc[i][j], 0, 0, 0);
        acc[i][j] = __builtin_amdgcn_mfma_f32_16x16x32_bf16(al[i], bh[j], acc[i][j], 0, 0, 0);
      }
    }
  }
}

// epilogue; act: 0 none, 1 relu, 2 lrelu, 3 final-scatter, 4 bf16-store
__device__ inline void epilogue(f32x4 acc[2][2], const float* bias, const float* res,
                                float* out, int N, int m0, int n0,
                                int wr, int wc, int lane, int act) {
  int colb = n0 + wc*32 + (lane & 15);
  int rowb = m0 + wr*32 + ((lane >> 4) << 2);
  #pragma unroll
  for (int j = 0; j < 2; ++j) {
    int cc = colb + j*16;
    if (cc >= N) continue;
    float bv = bias ? bias[cc] : 0.f;
    #pragma unroll
    for (int i = 0; i < 2; ++i) {
      #pragma unroll
      for (int r = 0; r < 4; ++r) {
        int rr = rowb + i*16 + r;
        float v = acc[i][j][r] + bv;
        if (act == 1) v = fmaxf(v, 0.f);
        else if (act == 2) v = v > 0.f ? v : 0.2f*v;
        if (res) v += res[(long)rr*N + cc];
        if (act == 3) {
          int hh = rr / 48, ww2 = rr % 48, q = cc / 3, ch = cc % 3;
          out[ch*57600 + ((q/5)*48 + hh)*240 + (q%5)*48 + ww2] = v;
        } else if (act == 4) {
          ((ushort*)out)[(long)rr*N + cc] = f2bf(v);
        } else {
          out[(long)rr*N + cc] = v;
        }
      }
    }
  }
}

// ---------------- qkvg: qkv GEMM grouped by A-plane type ----------------
template<int K>
__global__ __launch_bounds__(256) void qkvg_k(
    const float* __restrict__ A, const float* __restrict__ pe, int pe_mode,
    const float* __restrict__ g, const float* __restrict__ bb,
    const float* __restrict__ W, float* __restrict__ out,
    int NTr0, int NTr1, int N, int Mreal, int Mpad) {
  constexpr int NCH = K / 64;
  __shared__ char Apl[NCH * 16384];
  __shared__ char Bp[16384];
  __shared__ float sw_[4][64][2];
  __shared__ float sf_[64][2];
  int bid = blockIdx.x;
  int type = bid / Mpad, m = bid % Mpad;
  if (m >= Mreal) return;
  int m0 = m*64;
  int NTr = type ? NTr1 : NTr0;
  int ntbase = type ? NTr0 : 0;
  int t = threadIdx.x, lane = t & 63, wave = t >> 6;
  int wr = wave >> 1, wc = wave & 1;

  if (type == 0) {
    f32x4 rv[NCH][4];
    float sA[4], sQ[4];
    #pragma unroll
    for (int i = 0; i < 4; ++i) { sA[i] = 0.f; sQ[i] = 0.f; }
    #pragma unroll
    for (int ch = 0; ch < NCH; ++ch)
      #pragma unroll
      for (int i = 0; i < 4; ++i) {
        int row, kof, wo;
        slot_decode(i, wave, lane, row, kof, wo);
        int gk = ch*64 + kof;
        f32x4 av = *(const f32x4*)&A[(long)(m0 + row)*K + gk];
        if (pe_mode == 0)      av += *(const f32x4*)&pe[(long)(m0/576)*K + gk];
        else                   av += *(const f32x4*)&pe[(long)(m0%576 + row)*K + gk];
        rv[ch][i] = av;
        #pragma unroll
        for (int e = 0; e < 4; ++e) { sA[i] += av[e]; sQ[i] = fmaf(av[e], av[e], sQ[i]); }
      }
    #pragma unroll
    for (int i = 0; i < 4; ++i) {
      float s = sA[i], q = sQ[i];
      s += __shfl_xor(s, 1, 64);  q += __shfl_xor(q, 1, 64);
      s += __shfl_xor(s, 32, 64); q += __shfl_xor(q, 32, 64);
      if ((lane & 1) == 0 && lane < 32) {
        int row = i*16 + (lane >> 1);
        sw_[wave][row][0] = s; sw_[wave][row][1] = q;
      }
    }
    __syncthreads();
    if (t < 64) {
      float s = sw_[0][t][0] + sw_[1][t][0] + sw_[2][t][0] + sw_[3][t][0];
      float q = sw_[0][t][1] + sw_[1][t][1] + sw_[2][t][1] + sw_[3][t][1];
      float mean = s / K, var = q / K - mean*mean;
      sf_[t][0] = mean; sf_[t][1] = rsqrtf(var + 1e-5f);
    }
    __syncthreads();
    #pragma unroll
    for (int ch = 0; ch < NCH; ++ch)
      #pragma unroll
      for (int i = 0; i < 4; ++i) {
        int row, kof, wo;
        slot_decode(i, wave, lane, row, kof, wo);
        int gk = ch*64 + kof;
        float mean = sf_[row][0], rstd = sf_[row][1];
        f32x4 gv = *(const f32x4*)&g[gk];
        f32x4 bv = *(const f32x4*)&bb[gk];
        f32x4 nv;
        #pragma unroll
        for (int e = 0; e < 4; ++e) nv[e] = (rv[ch][i][e] - mean)*rstd*gv[e] + bv[e];
        store_split(Apl + ch*16384 + wo, nv);
      }
  } else {
    #pragma unroll
    for (int ch = 0; ch < NCH; ++ch)
      #pragma unroll
      for (int i = 0; i < 4; ++i) {
        int row, kof, wo;
        slot_decode(i, wave, lane, row, kof, wo);
        f32x4 av = *(const f32x4*)&A[(long)(m0 + row)*K + ch*64 + kof];
        store_split(Apl + ch*16384 + wo, av);
      }
  }

  int S = NTr * NCH;
  f32x4 pb[4];
  #pragma unroll
  for (int i = 0; i < 4; ++i) {
    int row, kof, wo;
    slot_decode(i, wave, lane, row, kof, wo);
    pb[i] = *(const f32x4*)&W[(long)(ntbase*64 + row)*K + kof];
  }
  f32x4 acc[2][2];
  #pragma unroll
  for (int i = 0; i < 2; ++i)
    #pragma unroll
    for (int j = 0; j < 2; ++j) acc[i][j] = (f32x4){0.f,0.f,0.f,0.f};
  for (int s = 0; s < S; ++s) {
    int nt = s / NCH, ch = s % NCH;
    __syncthreads();
    #pragma unroll
    for (int i = 0; i < 4; ++i) {
      int row, kof, wo;
      slot_decode(i, wave, lane, row, kof, wo);
      store_split(Bp + wo, pb[i]);
    }
    __syncthreads();
    if (s + 1 < S) {
      int ntn = (s+1) / NCH, chn = (s+1) % NCH;
      #pragma unroll
      for (int i = 0; i < 4; ++i) {
        int row, kof, wo;
        slot_decode(i, wave, lane, row, kof, wo);
        pb[i] = *(const f32x4*)&W[(long)((ntbase+ntn)*64 + row)*K + chn*64 + kof];
      }
    }
    mfma_step(Apl + ch*16384, Bp, lane, wr, wc, acc);
    if (ch == NCH - 1) {
      epilogue(acc, nullptr, nullptr, out, N, m0, (ntbase+nt)*64, wr, wc, lane, 4);
      #pragma unroll
      for (int i = 0; i < 2; ++i)
        #pragma unroll
        for (int j = 0; j < 2; ++j) acc[i][j] = (f32x4){0.f,0.f,0.f,0.f};
    }
  }
}

// ---------------- mgemm3 (imp-MLP tail only) ----------------
template<int K, int LN>
__global__ __launch_bounds__(256) void mgemm3_k(
    const float* __restrict__ A, const float* __restrict__ A2, int nsplit,
    const float* __restrict__ pe, int pe_mode,
    const float* __restrict__ g, const float* __restrict__ bb,
    const float* __restrict__ W, const float* __restrict__ bias,
    const float* __restrict__ res, float* __restrict__ out,
    int N, int act, int Mreal, int Mpad) {
  constexpr int NCH = K / 64;
  __shared__ char Apl[NCH * 16384];
  __shared__ char Bp[16384];
  int bid = blockIdx.x;
  int m = bid % Mpad, nt = bid / Mpad;
  if (m >= Mreal) return;
  int m0 = m*64, n0 = nt*64;
  int t = threadIdx.x, lane = t & 63, wave = t >> 6;
  int wr = wave >> 1, wc = wave & 1;
  const float* As = LN ? A2 : A;
  #pragma unroll
  for (int ch = 0; ch < NCH; ++ch)
    #pragma unroll
    for (int i = 0; i < 4; ++i) {
      int row, kof, wo;
      slot_decode(i, wave, lane, row, kof, wo);
      f32x4 av = *(const f32x4*)&As[(long)(m0 + row)*K + ch*64 + kof];
      store_split(Apl + ch*16384 + wo, av);
    }
  f32x4 pb[4];
  #pragma unroll
  for (int i = 0; i < 4; ++i) {
    int row, kof, wo;
    slot_decode(i, wave, lane, row, kof, wo);
    int br = n0 + row;
    pb[i] = (br < N) ? *(const f32x4*)&W[(long)br*K + kof] : (f32x4){0.f,0.f,0.f,0.f};
  }
  __syncthreads();
  f32x4 acc[2][2];
  #pragma unroll
  for (int i = 0; i < 2; ++i)
    #pragma unroll
    for (int j = 0; j < 2; ++j) acc[i][j] = (f32x4){0.f,0.f,0.f,0.f};
  for (int ch = 0; ch < NCH; ++ch) {
    #pragma unroll
    for (int i = 0; i < 4; ++i) {
      int row, kof, wo;
      slot_decode(i, wave, lane, row, kof, wo);
      store_split(Bp + wo, pb[i]);
    }
    __syncthreads();
    if (ch + 1 < NCH) {
      #pragma unroll
      for (int i = 0; i < 4; ++i) {
        int row, kof, wo;
        slot_decode(i, wave, lane, row, kof, wo);
        int br = n0 + row;
        pb[i] = (br < N) ? *(const f32x4*)&W[(long)br*K + (ch+1)*64 + kof]
                         : (f32x4){0.f,0.f,0.f,0.f};
      }
    }
    mfma_step(Apl + ch*16384, Bp, lane, wr, wc, acc);
    if (ch + 1 < NCH) __syncthreads();
  }
  epilogue(acc, bias, res, out, N, m0, n0, wr, wc, lane, act);
}

// ---------------- cgemm3: 3x3 conv as 9 shifted GEMMs ----------------
__global__ __launch_bounds__(256) void cgemm3_k(
    const float* __restrict__ in, const float* __restrict__ W9, long wstride,
    const float* __restrict__ res, float* __restrict__ out, long ostride,
    int N, int act, int Mreal, int Mpad) {
  __shared__ float halo[144 * 68];
  __shared__ char Ap[16384], Bp[16384];
  int bid = blockIdx.x;
  int m = bid % Mpad, nt = bid / Mpad;
  if (m >= Mreal) return;
  int ly = blockIdx.y;
  W9  += (long)ly * wstride;
  out += (long)ly * ostride;
  int m0 = m*64, n0 = nt*64;
  int a = m0 / 576, off = m0 % 576;
  int h_lo = off/24 - 1, h_hi = (off + 63)/24 + 1;
  int RH = h_hi - h_lo + 1;
  int t = threadIdx.x, lane = t & 63, wave = t >> 6;
  int wr = wave >> 1, wc = wave & 1;
  for (int sidx = t; sidx < RH*24*16; sidx += 256) {
    int tokr = sidx >> 4, c4 = (sidx & 15) << 2;
    int h = h_lo + tokr/24, w = tokr % 24;
    f32x4 v = {0.f,0.f,0.f,0.f};
    if ((unsigned)h < 24u) v = *(const f32x4*)&in[(long)(a*576 + h*24 + w)*64 + c4];
    *(f32x4*)&halo[tokr*68 + c4] = v;
  }
  f32x4 pb[4];
  #pragma unroll
  for (int i = 0; i < 4; ++i) {
    int row, kof, wo;
    slot_decode(i, wave, lane, row, kof, wo);
    int br = n0 + row;
    pb[i] = (br < N) ? *(const f32x4*)&W9[(long)br*64 + kof] : (f32x4){0.f,0.f,0.f,0.f};
  }
  __syncthreads();
  f32x4 acc[2][2];
  #pragma unroll
  for (int i = 0; i < 2; ++i)
    #pragma unroll
    for (int j = 0; j < 2; ++j) acc[i][j] = (f32x4){0.f,0.f,0.f,0.f};
  for (int ij = 0; ij < 9; ++ij) {
    int di = ij/3 - 1, dj = ij%3 - 1;
    #pragma unroll
    for (int i = 0; i < 4; ++i) {
      int row, kof, wo;
      slot_decode(i, wave, lane, row, kof, wo);
      int tok = off + row;
      int h2 = tok/24 + di, w2 = tok%24 + dj;
      f32x4 v = {0.f,0.f,0.f,0.f};
      if ((unsigned)h2 < 24u && (unsigned)w2 < 24u)
        v = *(const f32x4*)&halo[((h2 - h_lo)*24 + w2)*68 + kof];
      store_split(Ap + wo, v);
      store_split(Bp + wo, pb[i]);
    }
    __syncthreads();
    if (ij < 8) {
      #pragma unroll
      for (int i = 0; i < 4; ++i) {
        int row, kof, wo;
        slot_decode(i, wave, lane, row, kof, wo);
        int br = n0 + row;
        pb[i] = (br < N) ? *(const f32x4*)&W9[((long)(ij+1)*N + br)*64 + kof]
                         : (f32x4){0.f,0.f,0.f,0.f};
      }
    }
    mfma_step(Ap, Bp, lane, wr, wc, acc);
    if (ij < 8) __syncthreads();
  }
  epilogue(acc, nullptr, res, out, N, m0, n0, wr, wc, lane, act);
}

// ---------------- ang_mega ----------------
__global__ __launch_bounds__(256) void ang_mega_k(
    const ushort* __restrict__ qkv, const float* __restrict__ Wout,
    const float* __restrict__ blkr, const float* __restrict__ g,
    const float* __restrict__ bb, float* __restrict__ atok, float* __restrict__ tnf) {
  int hw = blockIdx.x;
  __shared__ float lq[25*192];
  __shared__ float lao[25*64];
  __shared__ float po[25*68];
  __shared__ float wout[64*65];
  __shared__ float st[25][2];
  int t = threadIdx.x;
  for (int idx = t; idx < 600; idx += 256) {
    int a3 = idx / 24, c8 = (idx % 24) * 8;
    s16x8 r = *(const s16x8*)&qkv[(long)(a3*576 + hw)*192 + c8];
    #pragma unroll
    for (int e = 0; e < 8; ++e) lq[a3*192 + c8 + e] = bf2f((ushort)r[e]);
  }
  for (int idx = t; idx < 4096; idx += 256) {
    int c = idx >> 6, d = idx & 63;
    wout[c*65 + d] = Wout[idx];
  }
  __syncthreads();
  if (t < 200) {
    int l = t / 8, head = t & 7;
    const float* q = lq + l*192 + head*8;
    float s[25]; float mx = -1e30f;
    #pragma unroll
    for (int mm = 0; mm < 25; ++mm) {
      const float* kk = lq + mm*192 + 64 + head*8;
      float acc = 0.f;
      #pragma unroll
      for (int d = 0; d < 8; ++d) acc = fmaf(q[d], kk[d], acc);
      acc *= 0.3535533905932738f;
      s[mm] = acc; mx = fmaxf(mx, acc);
    }
    float sum = 0.f;
    #pragma unroll
    for (int mm = 0; mm < 25; ++mm) { s[mm] = expf(s[mm] - mx); sum += s[mm]; }
    float inv = 1.f / sum;
    #pragma unroll
    for (int d = 0; d < 8; ++d) {
      float acc = 0.f;
      #pragma unroll
      for (int mm = 0; mm < 25; ++mm) acc = fmaf(s[mm], lq[mm*192 + 128 + head*8 + d], acc);
      lao[l*64 + head*8 + d] = acc * inv;
    }
  }
  __syncthreads();
  for (int idx = t; idx < 1600; idx += 256) {
    int tok = idx >> 6, c = idx & 63;
    const float* ar = &lao[tok*64];
    const float* wr = &wout[c*65];
    float accp = 0.f;
    #pragma unroll 16
    for (int d = 0; d < 64; ++d) accp = fmaf(ar[d], wr[d], accp);
    po[tok*68 + c] = accp + blkr[(long)(tok*576 + hw)*64 + c];
  }
  __syncthreads();
  if (t < 25) {
    float s = 0.f, q = 0.f;
    for (int c = 0; c < 64; ++c) { float x = po[t*68 + c]; s += x; q = fmaf(x, x, q); }
    float mean = s / 64.f, var = q / 64.f - mean*mean;
    st[t][0] = mean; st[t][1] = rsqrtf(var + 1e-5f);
  }
  __syncthreads();
  for (int idx = t; idx < 1600; idx += 256) {
    int tok = idx >> 6, c = idx & 63;
    float x = po[tok*68 + c];
    long gidx = (long)(tok*576 + hw)*64 + c;
    atok[gidx] = x;
    tnf[gidx] = (x - st[tok][0]) * st[tok][1] * g[c] + bb[c];
  }
}

// ---------------- ffn_ang ----------------
__global__ __launch_bounds__(256) void ffn_ang_k(
    const float* __restrict__ tnf, const float* __restrict__ w1,
    const float* __restrict__ w2, float* __restrict__ atok,
    int Mreal, int Mpad) {
  __shared__ char Ap[16384], Bp[16384], Hp[2][16384];
  int bid = blockIdx.x;
  int m = bid % Mpad;
  if (m >= Mreal) return;
  int m0 = m*64;
  int t = threadIdx.x, lane = t & 63, wave = t >> 6;
  int wr = wave >> 1, wc = wave & 1;
  #pragma unroll
  for (int i = 0; i < 4; ++i) {
    int row, kof, wo;
    slot_decode(i, wave, lane, row, kof, wo);
    f32x4 av = *(const f32x4*)&tnf[(long)(m0 + row)*64 + kof];
    store_split(Ap + wo, av);
  }
  f32x4 pb[4];
  #pragma unroll
  for (int i = 0; i < 4; ++i) {
    int row, kof, wo;
    slot_decode(i, wave, lane, row, kof, wo);
    pb[i] = *(const f32x4*)&w1[(long)row*64 + kof];
  }
  __syncthreads();
  for (int nt = 0; nt < 2; ++nt) {
    #pragma unroll
    for (int i = 0; i < 4; ++i) {
      int row, kof, wo;
      slot_decode(i, wave, lane, row, kof, wo);
      store_split(Bp + wo, pb[i]);
    }
    __syncthreads();
    #pragma unroll
    for (int i = 0; i < 4; ++i) {
      int row, kof, wo;
      slot_decode(i, wave, lane, row, kof, wo);
      pb[i] = (nt == 0) ? *(const f32x4*)&w1[(long)(64 + row)*64 + kof]
                        : *(const f32x4*)&w2[(long)row*128 + kof];
    }
    f32x4 acc[2][2];
    #pragma unroll
    for (int i = 0; i < 2; ++i)
      #pragma unroll
      for (int j = 0; j < 2; ++j) acc[i][j] = (f32x4){0.f,0.f,0.f,0.f};
    mfma_step(Ap, Bp, lane, wr, wc, acc);
    #pragma unroll
    for (int jj = 0; jj < 2; ++jj)
      #pragma unroll
      for (int ii = 0; ii < 2; ++ii)
        #pragma unroll
        for (int r = 0; r < 4; ++r) {
          int rr = wr*32 + ii*16 + ((lane >> 4) << 2) + r;
          int cc = wc*32 + jj*16 + (lane & 15);
          scatter_split(Hp[nt], rr, cc, fmaxf(acc[ii][jj][r], 0.f));
        }
    __syncthreads();
  }
  f32x4 acc2[2][2];
  #pragma unroll
  for (int i = 0; i < 2; ++i)
    #pragma unroll
    for (int j = 0; j < 2; ++j) acc2[i][j] = (f32x4){0.f,0.f,0.f,0.f};
  for (int ch = 0; ch < 2; ++ch) {
    #pragma unroll
    for (int i = 0; i < 4; ++i) {
      int row, kof, wo;
      slot_decode(i, wave, lane, row, kof, wo);
      store_split(Bp + wo, pb[i]);
    }
    __syncthreads();
    if (ch == 0) {
      #pragma unroll
      for (int i = 0; i < 4; ++i) {
        int row, kof, wo;
        slot_decode(i, wave, lane, row, kof, wo);
        pb[i] = *(const f32x4*)&w2[(long)row*128 + 64 + kof];
      }
    }
    mfma_step(Hp[ch], Bp, lane, wr, wc, acc2);
    if (ch == 0) __syncthreads();
  }
  epilogue(acc2, nullptr, atok, atok, 64, m0, 0, wr, wc, lane, 0);
}

// ---------------- megaspa (512 threads, direct-load attention, wout prefetch) ----------------
__global__ __launch_bounds__(512) void megaspa_k(
    const ushort* __restrict__ qkv, const float* __restrict__ stok,
    const float* __restrict__ wout, const float* __restrict__ g,
    const float* __restrict__ bb, const float* __restrict__ w1,
    const float* __restrict__ w2, const float* __restrict__ wlin,
    float* __restrict__ outb, int Mreal, int Mpad) {
  __shared__ char Aop[32768];
  __shared__ char SCR[65536];
  __shared__ float Rf[64*132];
  __shared__ float st[64][2];
  int bid = blockIdx.x;
  int m = bid % Mpad;
  if (m >= Mreal) return;
  int m0 = m*64;
  int t = threadIdx.x, lane = t & 63, wave = t >> 6;
  int wgrp = wave >> 2, w4 = wave & 3;
  int wr = w4 >> 1, wc = w4 & 1;
  char* Bp  = SCR + wgrp*16384;
  char* Hp0 = SCR + 32768;
  char* Hp1 = SCR + 49152;

  // ---- Phase 0: stage stok residual into Rf; prefetch phase-2 wout tiles ----
  for (int idx = t; idx < 2048; idx += 512) {
    int row = idx >> 5, c4 = (idx & 31) << 2;
    *(f32x4*)&Rf[row*132 + c4] = *(const f32x4*)&stok[(long)(m0 + row)*128 + c4];
  }
  f32x4 pw[2][4];
  #pragma unroll
  for (int ch = 0; ch < 2; ++ch)
    #pragma unroll
    for (int i = 0; i < 4; ++i) {
      int row, kof, wo;
      slot_decode(i, w4, lane, row, kof, wo);
      pw[ch][i] = *(const f32x4*)&wout[(long)(wgrp*64 + row)*128 + ch*64 + kof];
    }

  // ---- Phase 1: windowed attention (1 task/thread), batched clamped global loads ----
  {
    int rr1 = t >> 3, head = t & 7;
    int x = m0 + rr1;
    int hw = x % 576, h = hw / 24, w = hw % 24;
    float qr[16];
    ld_bf16x16(qkv + (long)x*384 + head*16, qr);
    float s[25]; float mx = -1e30f;
    #pragma unroll
    for (int ro = 0; ro < 5; ++ro) {
      int h2 = h + ro - 2;
      s16x8 k0[5], k1[5];
      #pragma unroll
      for (int co = 0; co < 5; ++co) {
        int xt = x + (ro - 2)*24 + (co - 2);
        xt = min(max(xt, 0), 14399);
        const ushort* kp = qkv + (long)xt*384 + 128 + head*16;
        k0[co] = *(const s16x8*)kp;
        k1[co] = *(const s16x8*)(kp + 8);
      }
      #pragma unroll
      for (int co = 0; co < 5; ++co) {
        int w2c = w + co - 2;
        float sc = -1e30f;
        if (h2 >= 0 && h2 < 24 && w2c >= 0 && w2c < 24) {
          sc = 0.f;
          #pragma unroll
          for (int d = 0; d < 8; ++d) sc = fmaf(qr[d], bf2f((ushort)k0[co][d]), sc);
          #pragma unroll
          for (int d = 0; d < 8; ++d) sc = fmaf(qr[8+d], bf2f((ushort)k1[co][d]), sc);
          sc *= 0.25f;
        }
        s[ro*5 + co] = sc; mx = fmaxf(mx, sc);
      }
    }
    float sum = 0.f;
    #pragma unroll
    for (int i = 0; i < 25; ++i) {
      float e = (s[i] > -1e29f) ? expf(s[i] - mx) : 0.f;
      s[i] = e; sum += e;
    }
    float inv = 1.f / sum;
    float acc[16];
    #pragma unroll
    for (int d = 0; d < 16; ++d) acc[d] = 0.f;
    #pragma unroll
    for (int ro = 0; ro < 5; ++ro) {
      s16x8 v0[5], v1[5];
      #pragma unroll
      for (int co = 0; co < 5; ++co) {
        int xt = x + (ro - 2)*24 + (co - 2);
        xt = min(max(xt, 0), 14399);
        const ushort* vp = qkv + (long)xt*384 + 256 + head*16;
        v0[co] = *(const s16x8*)vp;
        v1[co] = *(const s16x8*)(vp + 8);
      }
      #pragma unroll
      for (int co = 0; co < 5; ++co) {
        float sv = s[ro*5 + co];
        #pragma unroll
        for (int d = 0; d < 8; ++d) acc[d] = fmaf(sv, bf2f((ushort)v0[co][d]), acc[d]);
        #pragma unroll
        for (int d = 0; d < 8; ++d) acc[8+d] = fmaf(sv, bf2f((ushort)v1[co][d]), acc[8+d]);
      }
    }
    #pragma unroll
    for (int d = 0; d < 16; ++d) {
      int cc = head*16 + d;
      scatter_split(Aop + (cc >> 6)*16384, rr1, cc & 63, acc[d] * inv);
    }
  }

  // ---- Phase 2: proj + residual -> Rf (wave-group nt split, prefetched B) ----
  {
    int nt = wgrp;
    f32x4 acc[2][2];
    #pragma unroll
    for (int i = 0; i < 2; ++i)
      #pragma unroll
      for (int j = 0; j < 2; ++j) acc[i][j] = (f32x4){0.f,0.f,0.f,0.f};
    for (int ch = 0; ch < 2; ++ch) {
      __syncthreads();
      #pragma unroll
      for (int i = 0; i < 4; ++i) {
        int row, kof, wo;
        slot_decode(i, w4, lane, row, kof, wo);
        store_split(Bp + wo, pw[ch][i]);
      }
      __syncthreads();
      mfma_step(Aop + ch*16384, Bp, lane, wr, wc, acc);
    }
    int colb = nt*64 + wc*32 + (lane & 15);
    int rowb = wr*32 + ((lane >> 4) << 2);
    #pragma unroll
    for (int j = 0; j < 2; ++j)
      #pragma unroll
      for (int i = 0; i < 2; ++i)
        #pragma unroll
        for (int r = 0; r < 4; ++r) {
          int rr = rowb + i*16 + r, cc = colb + j*16;
          Rf[rr*132 + cc] += acc[i][j][r];
        }
  }
  __syncthreads();

  // ---- Phase 3: LN (8 threads/row over padded Rf) -> normed planes (ch = wgrp) ----
  {
    int row = t >> 3, q8 = t & 7;
    const float* yr = &Rf[row*132 + q8*16];
    float sm = 0.f, sq = 0.f;
    #pragma unroll
    for (int j2 = 0; j2 < 16; ++j2) { float xv = yr[j2]; sm += xv; sq = fmaf(xv, xv, sq); }
    sm += __shfl_xor(sm, 1, 64); sq += __shfl_xor(sq, 1, 64);
    sm += __shfl_xor(sm, 2, 64); sq += __shfl_xor(sq, 2, 64);
    sm += __shfl_xor(sm, 4, 64); sq += __shfl_xor(sq, 4, 64);
    if (q8 == 0) {
      float mean = sm / 128.f, var = sq / 128.f - mean*mean;
      st[row][0] = mean; st[row][1] = rsqrtf(var + 1e-5f);
    }
  }
  __syncthreads();
  {
    int ch = wgrp;
    #pragma unroll
    for (int i = 0; i < 4; ++i) {
      int row, kof, wo;
      slot_decode(i, w4, lane, row, kof, wo);
      int gk = ch*64 + kof;
      f32x4 xv = *(const f32x4*)&Rf[row*132 + gk];
      float mean = st[row][0], rstd = st[row][1];
      f32x4 gv = *(const f32x4*)&g[gk];
      f32x4 bv = *(const f32x4*)&bb[gk];
      f32x4 nv;
      #pragma unroll
      for (int e = 0; e < 4; ++e) nv[e] = (xv[e] - mean)*rstd*gv[e] + bv[e];
      store_split(Aop + ch*16384 + wo, nv);
    }
  }

  // ---- Phase 4+5: FFN1/FFN2 interleaved, 2 rounds; acc2 persists ----
  f32x4 acc2[2][2];
  #pragma unroll
  for (int i = 0; i < 2; ++i)
    #pragma unroll
    for (int j = 0; j < 2; ++j) acc2[i][j] = (f32x4){0.f,0.f,0.f,0.f};
  for (int r = 0; r < 2; ++r) {
    int nt = 2*r + wgrp;
    f32x4 accH[2][2];
    #pragma unroll
    for (int i = 0; i < 2; ++i)
      #pragma unroll
      for (int j = 0; j < 2; ++j) accH[i][j] = (f32x4){0.f,0.f,0.f,0.f};
    for (int ch = 0; ch < 2; ++ch) {
      __syncthreads();
      #pragma unroll
      for (int i = 0; i < 4; ++i) {
        int row, kof, wo;
        slot_decode(i, w4, lane, row, kof, wo);
        f32x4 bv = *(const f32x4*)&w1[(long)(nt*64 + row)*128 + ch*64 + kof];
        store_split(Bp + wo, bv);
      }
      __syncthreads();
      mfma_step(Aop + ch*16384, Bp, lane, wr, wc, accH);
    }
    char* Hpw = wgrp ? Hp1 : Hp0;
    #pragma unroll
    for (int jj = 0; jj < 2; ++jj)
      #pragma unroll
      for (int ii = 0; ii < 2; ++ii)
        #pragma unroll
        for (int rx = 0; rx < 4; ++rx) {
          int rr = wr*32 + ii*16 + ((lane >> 4) << 2) + rx;
          int cc = wc*32 + jj*16 + (lane & 15);
          scatter_split(Hpw, rr, cc, fmaxf(accH[ii][jj][rx], 0.f));
        }
    for (int q = 0; q < 2; ++q) {
      __syncthreads();
      #pragma unroll
      for (int i = 0; i < 4; ++i) {
        int row, kof, wo;
        slot_decode(i, w4, lane, row, kof, wo);
        f32x4 bv = *(const f32x4*)&w2[(long)(wgrp*64 + row)*256 + (2*r + q)*64 + kof];
        store_split(Bp + wo, bv);
      }
      __syncthreads();
      mfma_step(q ? Hp1 : Hp0, Bp, lane, wr, wc, acc2);
    }
  }
  {
    int colb = wc*32 + (lane & 15);
    int rowb = wr*32 + ((lane >> 4) << 2);
    #pragma unroll
    for (int jj = 0; jj < 2; ++jj)
      #pragma unroll
      for (int ii = 0; ii < 2; ++ii)
        #pragma unroll
        for (int rx = 0; rx < 4; ++rx) {
          int rr = rowb + ii*16 + rx;
          int cc = colb + jj*16;
          scatter_split(Aop + wgrp*16384, rr, cc,
                        acc2[ii][jj][rx] + Rf[rr*132 + wgrp*64 + cc]);
        }
  }

  // ---- Phase 6: spa_lin -> blk (wgrp 0 only; wgrp 1 matches barriers) ----
  f32x4 acc3[2][2];
  #pragma unroll
  for (int i = 0; i < 2; ++i)
    #pragma unroll
    for (int j = 0; j < 2; ++j) acc3[i][j] = (f32x4){0.f,0.f,0.f,0.f};
  for (int ch = 0; ch < 2; ++ch) {
    __syncthreads();
    if (wgrp == 0) {
      #pragma unroll
      for (int i = 0; i < 4; ++i) {
        int row, kof, wo;
        slot_decode(i, w4, lane, row, kof, wo);
        f32x4 bv = *(const f32x4*)&wlin[(long)row*128 + ch*64 + kof];
        store_split(SCR + wo, bv);
      }
    }
    __syncthreads();
    if (wgrp == 0) mfma_step(Aop + ch*16384, SCR, lane, wr, wc, acc3);
  }
  if (wgrp == 0)
    epilogue(acc3, nullptr, nullptr, outb, 64, m0, 0, wr, wc, lane, 0);
}

// ---------------- zgemm3 ----------------
__global__ __launch_bounds__(256) void zgemm3_k(
    const float* __restrict__ buf, const float* __restrict__ blk,
    const float* __restrict__ W0, float* __restrict__ Zp) {
  __shared__ char Ap[16384], Bp[16384];
  int bid = blockIdx.x;
  int m = bid % 9;
  int nz = bid / 9;
  int n = nz % 5, z = nz / 5;
  int m0 = m*64, n0 = n*64;
  int t = threadIdx.x, lane = t & 63, wave = t >> 6;
  int wr = wave >> 1, wc = wave & 1;
  f32x4 pa[4], pb[4];
  #pragma unroll
  for (int i = 0; i < 4; ++i) {
    int row, kof, wo;
    slot_decode(i, wave, lane, row, kof, wo);
    long tok = (long)(z*5)*576 + m0 + row;
    pa[i] = *(const f32x4*)&buf[tok*64 + kof];
    pa[i] += *(const f32x4*)&blk[tok*64 + kof];
    pb[i] = *(const f32x4*)&W0[(long)(n0 + row)*1652 + (z*5)*64 + kof];
  }
  f32x4 acc[2][2];
  #pragma unroll
  for (int i = 0; i < 2; ++i)
    #pragma unroll
    for (int j = 0; j < 2; ++j) acc[i][j] = (f32x4){0.f,0.f,0.f,0.f};
  for (int q = 0; q < 5; ++q) {
    #pragma unroll
    for (int i = 0; i < 4; ++i) {
      int row, kof, wo;
      slot_decode(i, wave, lane, row, kof, wo);
      store_split(Ap + wo, pa[i]);
      store_split(Bp + wo, pb[i]);
    }
    __syncthreads();
    if (q < 4) {
      #pragma unroll
      for (int i = 0; i < 4; ++i) {
        int row, kof, wo;
        slot_decode(i, wave, lane, row, kof, wo);
        long tok = (long)(z*5 + q + 1)*576 + m0 + row;
        pa[i] = *(const f32x4*)&buf[tok*64 + kof];
        pa[i] += *(const f32x4*)&blk[tok*64 + kof];
        pb[i] = *(const f32x4*)&W0[(long)(n0 + row)*1652 + (z*5 + q + 1)*64 + kof];
      }
    }
    mfma_step(Ap, Bp, lane, wr, wc, acc);
    if (q < 4) __syncthreads();
  }
  epilogue(acc, nullptr, nullptr, Zp + (long)z*184320, 320, m0, n0, wr, wc, lane, 0);
}

// ---------------- combine ----------------
__global__ void combine_k(const float* __restrict__ Zp, const float* __restrict__ cav,
                          const float* __restrict__ coord, float* __restrict__ h0out) {
  int gidx = blockIdx.x * 256 + threadIdx.x;
  if (gidx >= 2304 * 320) return;
  int p = gidx / 320, o = gidx % 320;
  int hh = p / 48, ww = p % 48;
  float sh = hh * 0.5f - 0.25f, sw = ww * 0.5f - 0.25f;
  int h0i = (int)floorf(sh); float fh = sh - h0i;
  int w0i = (int)floorf(sw); float fw = sw - w0i;
  int h0c = max(h0i, 0), h1c = min(h0i + 1, 23);
  int w0c = max(w0i, 0), w1c = min(w0i + 1, 23);
  int i00 = (h0c*24 + w0c)*320 + o, i01 = (h0c*24 + w1c)*320 + o;
  int i10 = (h1c*24 + w0c)*320 + o, i11 = (h1c*24 + w1c)*320 + o;
  float z00 = 0.f, z01 = 0.f, z10 = 0.f, z11 = 0.f;
  #pragma unroll
  for (int z = 0; z < 5; ++z) {
    const float* Zz = Zp + (long)z*184320;
    z00 += Zz[i00]; z01 += Zz[i01]; z10 += Zz[i10]; z11 += Zz[i11];
  }
  float v = (1.f-fh)*((1.f-fw)*z00 + fw*z01) + fh*((1.f-fw)*z10 + fw*z11);
  #pragma unroll
  for (int d = 0; d < 2; ++d) {
    float co = coord[p*2 + d];
    float cc = fminf(fmaxf(co + 1e-6f, -1.f + 1e-6f), 1.f - 1e-6f);
    float ix = rintf(((cc + 1.f)*24.f - 1.f)*0.5f);
    ix = fminf(fmaxf(ix, 0.f), 23.f);
    float q = -1.f + (2.f*ix + 1.f)/24.f;
    v = fmaf((co - q)*24.f, cav[320*(d+1) + o], v);
  }
  h0out[gidx] = fmaxf(v + cav[o], 0.f);
}

// ---------------- setup ----------------
__device__ inline float pe_val(int pos, int c) {
  int j = c & 31;
  float freq = powf(10000.f, -2.f * (float)j / 64.f);
  float arg = (float)pos * freq;
  return (c < 32) ? sinf(arg) : cosf(arg);
}

__global__ void setup_k(const float* __restrict__ lr, const float* __restrict__ convi_w,
                        const float* __restrict__ spa_mlp,
                        const float* __restrict__ imp_w0, const float* __restrict__ imp_b0,
                        float* pe25, float* spa_pe, float* X, float* w9c, float* w9s,
                        float* cav) {
  int g = blockIdx.x * 256 + threadIdx.x;
  if (g < 1600) { pe25[g] = pe_val(g >> 6, g & 63); return; }
  g -= 1600;
  if (g < 36864) {
    int hw = g >> 6, c = g & 63; int h = hw / 24, w = hw % 24;
    spa_pe[g] = 0.5f * (pe_val(h, c) + pe_val(w, c)); return;
  }
  g -= 36864;
  if (g < 14400) {
    int aa = g / 576, hw = g % 576, h = hw / 24, w = hw % 24;
    X[g] = lr[((aa/5)*24 + h)*120 + (aa%5)*24 + w]; return;
  }
  g -= 14400;
  if (g < 110592) {
    int cv = g / 36864, rem = g % 36864;
    int ij = rem / 4096, oc = rem % 4096;
    int o = oc >> 6, c = oc & 63;
    w9c[g] = convi_w[((long)(cv*64 + o)*64 + c)*9 + ij]; return;
  }
  g -= 110592;
  if (g < 294912) {
    int l = g / 73728, rem = g % 73728;
    int ij = rem / 8192, oc = rem % 8192;
    int o = oc >> 6, c = oc & 63;
    w9s[g] = spa_mlp[((long)(l*128 + o))*576 + c*9 + ij]; return;
  }
  g -= 294912;
  if (g < 320) {
    int o = g;
    float s = imp_b0[o];
    #pragma unroll
    for (int idx = 0; idx < 50; ++idx) {
      int pair = idx >> 1;
      float cvv = 0.5f + (float)((idx & 1) ? pair % 5 : pair / 5);
      s = fmaf(cvv, imp_w0[(long)o*1652 + 1602 + idx], s);
    }
    cav[o] = s;
    cav[320 + o] = imp_w0[(long)o*1652 + 1600];
    cav[640 + o] = imp_w0[(long)o*1652 + 1601];
  }
}

// ---------------- conv0 ----------------
__global__ void conv0_k(const float* __restrict__ X, const float* __restrict__ W,
                        float* __restrict__ out) {
  int sp = threadIdx.x >> 6, lane = threadIdx.x & 63;
  int strip = blockIdx.x * 4 + sp;
  int a = strip / 48, r = strip % 48, h = r >> 1, w0 = (r & 1) * 12;
  __shared__ float patch[4][3][16];
  if (lane < 42) {
    int i = lane / 14, col = lane % 14;
    int h2 = h + i - 1, w2 = w0 + col - 1;
    float v = 0.f;
    if ((unsigned)h2 < 24u && (unsigned)w2 < 24u) v = X[a*576 + h2*24 + w2];
    patch[sp][i][col] = v;
  }
  __syncthreads();
  float wv[9];
  #pragma unroll
  for (int q = 0; q < 9; ++q) wv[q] = W[lane*9 + q];
  #pragma unroll
  for (int p = 0; p < 12; ++p) {
    float acc = 0.f;
    #pragma unroll
    for (int i = 0; i < 3; ++i)
      #pragma unroll
      for (int j = 0; j < 3; ++j)
        acc = fmaf(patch[sp][i][p + j], wv[i*3 + j], acc);
    out[(long)(a*576 + h*24 + w0 + p)*64 + lane] = acc;
  }
}

// ---------------- host launch ----------------
extern "C" void kernel_launch(void* const* d_in, const int* in_sizes, int n_in,
                              void* d_out, int out_size, void* d_ws, size_t ws_size,
                              hipStream_t stream) {
  (void)in_sizes; (void)n_in; (void)out_size;
  if (ws_size < (size_t)WS_FLOATS * 4) return;
  float* ws = (float*)d_ws;

  const float* lr       = (const float*)d_in[0];
  const float* coord    = (const float*)d_in[1];
  const float* conv0_w  = (const float*)d_in[2];
  const float* convi_w  = (const float*)d_in[3];
  const float* ang_ln_g = (const float*)d_in[4];
  const float* ang_ln_b = (const float*)d_in[5];
  const float* ang_in   = (const float*)d_in[6];
  const float* ang_out  = (const float*)d_in[7];
  const float* ang_ff_g = (const float*)d_in[8];
  const float* ang_ff_b = (const float*)d_in[9];
  const float* ang_w1   = (const float*)d_in[10];
  const float* ang_w2   = (const float*)d_in[11];
  const float* spa_mlp  = (const float*)d_in[12];
  const float* spa_ln_g = (const float*)d_in[13];
  const float* spa_ln_b = (const float*)d_in[14];
  const float* spa_in   = (const float*)d_in[15];
  const float* spa_out  = (const float*)d_in[16];
  const float* spa_ff_g = (const float*)d_in[17];
  const float* spa_ff_b = (const float*)d_in[18];
  const float* spa_w1   = (const float*)d_in[19];
  const float* spa_w2   = (const float*)d_in[20];
  const float* spa_lin  = (const float*)d_in[21];
  const float* imp_w0   = (const float*)d_in[22];
  const float* imp_b0   = (const float*)d_in[23];
  const float* imp_w1   = (const float*)d_in[24];
  const float* imp_b1   = (const float*)d_in[25];
  const float* imp_w2   = (const float*)d_in[26];
  const float* imp_b2   = (const float*)d_in[27];

  float* pe25 = ws + PE25_;  float* spa_pe = ws + SPAPE_;  float* X = ws + X_;
  float* cav = ws + CAV_;    float* petok = ws + PETOK_;
  float* w9c = ws + W9C_;    float* w9s = ws + W9S_;
  float* buf = ws + BUF_;    float* blk = ws + BLK_;      float* atok = ws + ATOK_;
  float* tnf = ws + TNF_;    float* stok = ws + STOK_;
  float* qkvf = ws + QKV_;   ushort* qkvh = (ushort*)(ws + QKV_);
  float* t0 = ws + T0_;      float* t1 = ws + T1_;
  float* Zp = ws + ZP_;      float* h0 = ws + H0_;        float* h1 = ws + H1_;

  setup_k<<<1792, 256, 0, stream>>>(lr, convi_w, spa_mlp, imp_w0, imp_b0,
                                    pe25, spa_pe, X, w9c, w9s, cav);
  conv0_k<<<300, 256, 0, stream>>>(X, conv0_w, buf);
  cgemm3_k<<<dim3(232,1), 256, 0, stream>>>(buf, w9c,         0, nullptr, t0,  0, 64, 2, 225, 232);
  cgemm3_k<<<dim3(232,1), 256, 0, stream>>>(t0,  w9c + 36864, 0, nullptr, t1,  0, 64, 2, 225, 232);
  cgemm3_k<<<dim3(232,1), 256, 0, stream>>>(t1,  w9c + 73728, 0, buf,     buf, 0, 64, 2, 225, 232);
  cgemm3_k<<<dim3(32, 4), 256, 0, stream>>>(spa_pe, w9s, 73728, nullptr, petok, 73728,
                                            128, 0, 9, 16);

  for (int l = 0; l < 4; ++l) {
    const float* blkr = (l == 0) ? buf : blk;
    // ---- AngTrans ----
    qkvg_k<64><<<464, 256, 0, stream>>>(blkr, pe25, 0,
        ang_ln_g + l*64, ang_ln_b + l*64, ang_in + l*192*64, qkvf,
        2, 1, 192, 225, 232);
    ang_mega_k<<<576, 256, 0, stream>>>(qkvh, ang_out + l*64*64, blkr,
        ang_ff_g + l*64, ang_ff_b + l*64, atok, tnf);
    ffn_ang_k<<<232, 256, 0, stream>>>(tnf, ang_w1 + l*128*64, ang_w2 + l*64*128,
        atok, 225, 232);
    // ---- SpaTrans ----
    cgemm3_k<<<dim3(464,1), 256, 0, stream>>>(atok, w9s + l*73728, 0, nullptr, stok, 0,
        128, 0, 225, 232);
    qkvg_k<128><<<464, 256, 0, stream>>>(stok, petok + l*73728, 1,
        spa_ln_g + l*128, spa_ln_b + l*128, spa_in + l*384*128, qkvf,
        4, 2, 384, 225, 232);
    megaspa_k<<<232, 512, 0, stream>>>(qkvh, stok, spa_out + l*128*128,
        spa_ff_g + l*128, spa_ff_b + l*128, spa_w1 + l*256*128, spa_w2 + l*128*256,
        spa_lin + l*64*128, blk, 225, 232);
  }

  zgemm3_k<<<225, 256, 0, stream>>>(buf, blk, imp_w0, Zp);
  combine_k<<<2880, 256, 0, stream>>>(Zp, cav, coord, h0);
  mgemm3_k<320,0><<<200, 256, 0, stream>>>(h0, h0, 0, nullptr, -1, nullptr, nullptr,
      imp_w1, imp_b1, nullptr, h1, 320, 1, 36, 40);
  mgemm3_k<320,0><<<80, 256, 0, stream>>>(h1, h1, 0, nullptr, -1, nullptr, nullptr,
      imp_w2, imp_b2, nullptr, (float*)d_out, 75, 3, 36, 40);
}